// Round 17
// baseline (137.350 us; speedup 1.0000x reference)
//
#include <hip/hip_runtime.h>

#define BS 32
#define NE 512
#define DMODEL 512
#define HEADS 8
#define EMB 64
#define FFH 256
#define MTOK (BS*NE)   // 16384

typedef unsigned short u16;
typedef short v8s __attribute__((ext_vector_type(8)));
typedef float f32x4 __attribute__((ext_vector_type(4)));
typedef u16 u16x4 __attribute__((ext_vector_type(4)));

#define GLOAD16(G, L) \
  __builtin_amdgcn_global_load_lds((const __attribute__((address_space(1))) unsigned int*)(G), \
      (__attribute__((address_space(3))) unsigned int*)(L), 16, 0, 0)

static __device__ __forceinline__ unsigned cvt_pk_bf16(float lo, float hi) {
    unsigned r;
    asm("v_cvt_pk_bf16_f32 %0, %1, %2" : "=v"(r) : "v"(lo), "v"(hi));
    return r;
}

static __device__ __forceinline__ u16 f2bf_bits(float f) {
    unsigned u = __float_as_uint(f);
    u += 0x7fffu + ((u >> 16) & 1u);   // round-to-nearest-even
    return (u16)(u >> 16);
}
static __device__ __forceinline__ float bflo(unsigned w) { return __uint_as_float(w << 16); }
static __device__ __forceinline__ float bfhi(unsigned w) { return __uint_as_float(w & 0xffff0000u); }

// ---------------- fused conversion ----------------
// id<8192: x -> xb linear + xp packed [tok16][k8][16][8].
// 8192..11263: Wq/Wk/Wv -> Wp packed (row = output col 0..1535).
// 11264..11519: W1/W2 -> row-major transposed via LDS 32x32 tiles.
__global__ __launch_bounds__(256) void cvt_all_kernel(
    const float* __restrict__ x, u16* __restrict__ xb, u16* __restrict__ xp,
    const float* __restrict__ Wq, const float* __restrict__ Wk, const float* __restrict__ Wv,
    const float* __restrict__ W1, const float* __restrict__ W2,
    u16* __restrict__ Wp, u16* __restrict__ W1T, u16* __restrict__ W2T)
{
    const int id = blockIdx.x;
    const int tt = threadIdx.x;
    if (id < 8192) {
        int i = id*256 + tt;
        float4 v = ((const float4*)x)[i];
        u16x4 o = { f2bf_bits(v.x), f2bf_bits(v.y), f2bf_bits(v.z), f2bf_bits(v.w) };
        ((u16x4*)xb)[i] = o;
        int e = i * 4;
        int row = e >> 9, k = e & 511;
        *(u16x4*)(xp + ((size_t)(row >> 4)*64 + (k >> 3))*128 + (row & 15)*8 + (k & 7)) = o;
        return;
    }
    if (id < 11264) {                  // Wqkv -> packed
        int widx = (id - 8192)*256 + tt;   // 0..786431
        int w = widx >> 18, rem = widx & 262143;
        int k = rem >> 9, n = rem & 511;
        const float* src = (w == 0) ? Wq : (w == 1) ? Wk : Wv;
        int np = w*512 + n;
        Wp[((size_t)(np >> 4)*64 + (k >> 3))*128 + (np & 15)*8 + (k & 7)] = f2bf_bits(src[rem]);
        return;
    }
    __shared__ float T[32][33];
    const int t2 = id - 11264;         // 0..255
    const float* src; u16* dst; int ldsrc, lddst, sr, sc;
    if (t2 < 128) {                    // W1: 512x256, 16x8 tiles
        int tr = t2 >> 3, tc = t2 & 7;
        src = W1; ldsrc = 256; sr = tr*32; sc = tc*32;
        dst = W1T + (size_t)sc*512 + sr; lddst = 512;
    } else {                           // W2: 256x512, 8x16 tiles
        int t = t2 - 128;
        int tr = t >> 4, tc = t & 15;
        src = W2; ldsrc = 512; sr = tr*32; sc = tc*32;
        dst = W2T + (size_t)sc*256 + sr; lddst = 256;
    }
    {
        int r = tt >> 3, c4 = (tt & 7) << 2;
        float4 v = *(const float4*)(src + (size_t)(sr + r)*ldsrc + sc + c4);
        T[r][c4] = v.x; T[r][c4+1] = v.y; T[r][c4+2] = v.z; T[r][c4+3] = v.w;
    }
    __syncthreads();
    {
        int n = tt >> 3, k4 = (tt & 7) << 2;
        u16x4 o = { f2bf_bits(T[k4][n]), f2bf_bits(T[k4+1][n]),
                    f2bf_bits(T[k4+2][n]), f2bf_bits(T[k4+3][n]) };
        *(u16x4*)(dst + (size_t)n*lddst + k4) = o;
    }
}

// ---------------- fused QKV + attention: 1 block = 1 (b,h), 512 thr / 8 waves ----------------
// Pass q/k/v: register-streaming GEMMs (packed fragments from xp/Wp, no staging, no barriers),
// epilogues write q -> LDS bounce, k -> K_lds, v^T -> VT_lds (XOR chunk swizzles).
// Then the attention core (swapped QK^T, streaming no-max softmax, permuted-key PV).
// LDS: [0,64K) K_lds [512 tok][128B]; [64K,128K) bounce then VT [64 d][1024B].
__global__ __launch_bounds__(512) void fused_attn_kernel(
    const u16* __restrict__ xp, const u16* __restrict__ Wp,
    const float* __restrict__ bsQ, const float* __restrict__ bsK, const float* __restrict__ bsV,
    u16* __restrict__ O)
{
    extern __shared__ char smem[];
    const int b = blockIdx.x >> 3, h = blockIdx.x & 7;
    const int tid = threadIdx.x, wave = tid >> 6, lane = tid & 63;
    const int lr = lane & 15, lg = lane >> 4, lr7 = lr & 7;
    char* Bnc = smem + 65536;
    const float SCL = 0.18033688011112042f;   // 0.125*log2(e)

    // fragment base pointers (u16 units): frag(i, K32-step s) = base + i*8192 + s*512
    const u16* a0  = xp + ((size_t)(b*32 + wave*4)*64 + lg)*128 + lr*8;
    const u16* bq0 = Wp + ((size_t)(h*4      )*64 + lg)*128 + lr*8;
    const u16* bk0 = Wp + ((size_t)(32 + h*4 )*64 + lg)*128 + lr*8;
    const u16* bv0 = Wp + ((size_t)(64 + h*4 )*64 + lg)*128 + lr*8;

    // ---- streaming pass (ping-pong, r9 structure). SWAP: acc = C^T ----
    f32x4 acc[4][4];

    auto run_pass = [&](const u16* bb, bool swap) {
        #pragma unroll
        for (int i = 0; i < 4; ++i)
            #pragma unroll
            for (int j = 0; j < 4; ++j) acc[i][j] = f32x4{0.f,0.f,0.f,0.f};
        v8s afA[4], bfA[4], afB[4], bfB[4];
        #pragma unroll
        for (int i = 0; i < 4; ++i) { afA[i] = *(const v8s*)(a0 + i*8192); bfA[i] = *(const v8s*)(bb + i*8192); }
        #pragma unroll
        for (int tp = 0; tp < 8; ++tp) {
            #pragma unroll
            for (int i = 0; i < 4; ++i) {
                afB[i] = *(const v8s*)(a0 + (2*tp + 1)*512 + i*8192);
                bfB[i] = *(const v8s*)(bb + (2*tp + 1)*512 + i*8192);
            }
            #pragma unroll
            for (int i = 0; i < 4; ++i)
                #pragma unroll
                for (int j = 0; j < 4; ++j)
                    acc[i][j] = swap
                        ? __builtin_amdgcn_mfma_f32_16x16x32_bf16(bfA[j], afA[i], acc[i][j], 0, 0, 0)
                        : __builtin_amdgcn_mfma_f32_16x16x32_bf16(afA[i], bfA[j], acc[i][j], 0, 0, 0);
            if (tp < 7) {
                #pragma unroll
                for (int i = 0; i < 4; ++i) {
                    afA[i] = *(const v8s*)(a0 + (2*tp + 2)*512 + i*8192);
                    bfA[i] = *(const v8s*)(bb + (2*tp + 2)*512 + i*8192);
                }
            }
            #pragma unroll
            for (int i = 0; i < 4; ++i)
                #pragma unroll
                for (int j = 0; j < 4; ++j)
                    acc[i][j] = swap
                        ? __builtin_amdgcn_mfma_f32_16x16x32_bf16(bfB[j], afB[i], acc[i][j], 0, 0, 0)
                        : __builtin_amdgcn_mfma_f32_16x16x32_bf16(afB[i], bfB[j], acc[i][j], 0, 0, 0);
        }
    };

    // ---- q pass: swapped acc; lane: tok = wave*64+i*16+lr, d = j*16+lg*4+{0..3} ----
    run_pass(bq0, true);
    #pragma unroll
    for (int j = 0; j < 4; ++j) {
        float4 b4 = *(const float4*)(bsQ + h*64 + j*16 + lg*4);
        #pragma unroll
        for (int i = 0; i < 4; ++i) {
            int tok = wave*64 + i*16 + lr;
            float v0 = (acc[i][j][0] + b4.x)*SCL, v1 = (acc[i][j][1] + b4.y)*SCL;
            float v2 = (acc[i][j][2] + b4.z)*SCL, v3 = (acc[i][j][3] + b4.w)*SCL;
            int chunk = 2*j + (lg >> 1);
            *(uint2*)(Bnc + tok*128 + ((chunk ^ lr7) << 4) + (lg & 1)*8)
                = make_uint2(cvt_pk_bf16(v0, v1), cvt_pk_bf16(v2, v3));
        }
    }
    // qa extract (own wave's rows only; compiler orders ds ops)
    v8s qa[4][2];
    #pragma unroll
    for (int ti = 0; ti < 4; ++ti) {
        const char* qr = Bnc + (wave*64 + ti*16 + lr)*128;
        qa[ti][0] = *(const v8s*)(qr + ((lg ^ lr7) << 4));
        qa[ti][1] = *(const v8s*)(qr + (((4 | lg) ^ lr7) << 4));
    }

    // ---- k pass: swapped acc -> K_lds ----
    run_pass(bk0, true);
    #pragma unroll
    for (int j = 0; j < 4; ++j) {
        float4 b4 = *(const float4*)(bsK + h*64 + j*16 + lg*4);
        #pragma unroll
        for (int i = 0; i < 4; ++i) {
            int tok = wave*64 + i*16 + lr;
            float v0 = acc[i][j][0] + b4.x, v1 = acc[i][j][1] + b4.y;
            float v2 = acc[i][j][2] + b4.z, v3 = acc[i][j][3] + b4.w;
            int chunk = 2*j + (lg >> 1);
            *(uint2*)(smem + tok*128 + ((chunk ^ lr7) << 4) + (lg & 1)*8)
                = make_uint2(cvt_pk_bf16(v0, v1), cvt_pk_bf16(v2, v3));
        }
    }
    __syncthreads();   // all qa reads done + K visible

    // ---- v pass: normal acc; lane: d = j*16+lr, toks = wave*64+i*16+lg*4+{0..3} ----
    run_pass(bv0, false);
    #pragma unroll
    for (int j = 0; j < 4; ++j) {
        #pragma unroll
        for (int i = 0; i < 4; ++i) {
            int d = j*16 + lr;
            float bv = bsV[h*64 + d];
            int chunk = wave*8 + 2*i + (lg >> 1);
            *(uint2*)(Bnc + d*1024 + ((chunk ^ lr7) << 4) + (lg & 1)*8)
                = make_uint2(cvt_pk_bf16(acc[i][j][0] + bv, acc[i][j][1] + bv),
                             cvt_pk_bf16(acc[i][j][2] + bv, acc[i][j][3] + bv));
        }
    }
    __syncthreads();   // VT ready

    // ---- attention core (r14, LDS-adapted) ----
    const int q0 = wave*64;
    f32x4 o[4][4] = {};
    float ssum[4] = {0.f, 0.f, 0.f, 0.f};

    #pragma unroll 1
    for (int c = 0; c < 16; ++c) {
        const char* kr0 = (const char*)smem + ((2*c  )*16 + lr)*128;
        const char* kr1 = (const char*)smem + ((2*c+1)*16 + lr)*128;
        v8s kA0 = *(const v8s*)(kr0 + ((lg ^ lr7) << 4));
        v8s kA1 = *(const v8s*)(kr0 + (((4|lg) ^ lr7) << 4));
        v8s kB0 = *(const v8s*)(kr1 + ((lg ^ lr7) << 4));
        v8s kB1 = *(const v8s*)(kr1 + (((4|lg) ^ lr7) << 4));
        v8s vf[4];
        #pragma unroll
        for (int dt = 0; dt < 4; ++dt) {
            const char* vr = Bnc + (dt*16 + lr)*1024;
            int c0 = c*4 + (lg >> 1), rem = (lg & 1)*8;
            uint2 lo = *(const uint2*)(vr + (((c0    ) ^ lr7) << 4) + rem);
            uint2 hi = *(const uint2*)(vr + (((c0 + 2) ^ lr7) << 4) + rem);
            uint4 u = make_uint4(lo.x, lo.y, hi.x, hi.y);
            vf[dt] = *(v8s*)&u;
        }
        #pragma unroll
        for (int ti = 0; ti < 4; ++ti) {
            __builtin_amdgcn_s_setprio(1);
            f32x4 s0 = {0.f,0.f,0.f,0.f}, s1 = {0.f,0.f,0.f,0.f};
            s0 = __builtin_amdgcn_mfma_f32_16x16x32_bf16(kA0, qa[ti][0], s0, 0, 0, 0);
            s0 = __builtin_amdgcn_mfma_f32_16x16x32_bf16(kA1, qa[ti][1], s0, 0, 0, 0);
            s1 = __builtin_amdgcn_mfma_f32_16x16x32_bf16(kB0, qa[ti][0], s1, 0, 0, 0);
            s1 = __builtin_amdgcn_mfma_f32_16x16x32_bf16(kB1, qa[ti][1], s1, 0, 0, 0);
            __builtin_amdgcn_s_setprio(0);
            float p0 = exp2f(s0[0]), p1 = exp2f(s0[1]), p2 = exp2f(s0[2]), p3 = exp2f(s0[3]);
            float r0 = exp2f(s1[0]), r1 = exp2f(s1[1]), r2 = exp2f(s1[2]), r3 = exp2f(s1[3]);
            ssum[ti] += ((p0 + p1) + (p2 + p3)) + ((r0 + r1) + (r2 + r3));
            unsigned a0w = cvt_pk_bf16(p0, p1), a1w = cvt_pk_bf16(p2, p3);
            unsigned b0w = cvt_pk_bf16(r0, r1), b1w = cvt_pk_bf16(r2, r3);
            uint4 pu = make_uint4(a0w, a1w, b0w, b1w);
            v8s pb = *(v8s*)&pu;
            __builtin_amdgcn_s_setprio(1);
            #pragma unroll
            for (int dt = 0; dt < 4; ++dt)
                o[ti][dt] = __builtin_amdgcn_mfma_f32_16x16x32_bf16(vf[dt], pb, o[ti][dt], 0, 0, 0);
            __builtin_amdgcn_s_setprio(0);
        }
    }

    __syncthreads();   // K/VT dead; LDS reused for O transpose

    float rinv[4];
    #pragma unroll
    for (int ti = 0; ti < 4; ++ti) {
        float v = ssum[ti];
        v += __shfl_xor(v, 16);
        v += __shfl_xor(v, 32);
        rinv[ti] = 1.f / v;
    }

    char* ow = (char*)smem + wave*10240;
    #pragma unroll
    for (int ti = 0; ti < 4; ++ti) {
        #pragma unroll
        for (int dt = 0; dt < 4; ++dt) {
            unsigned d0 = cvt_pk_bf16(o[ti][dt][0]*rinv[ti], o[ti][dt][1]*rinv[ti]);
            unsigned d1 = cvt_pk_bf16(o[ti][dt][2]*rinv[ti], o[ti][dt][3]*rinv[ti]);
            *(uint2*)(ow + (ti*16 + lr)*160 + dt*32 + lg*8) = make_uint2(d0, d1);
        }
    }
    __asm__ volatile("s_waitcnt lgkmcnt(0)" ::: "memory");
    #pragma unroll
    for (int it = 0; it < 8; ++it) {
        int rr2 = it*8 + (lane >> 3);
        uint4 v = *(const uint4*)(ow + rr2*160 + (lane & 7)*16);
        *(uint4*)(O + (size_t)(b*NE + q0 + rr2)*DMODEL + h*EMB + (lane & 7)*8) = v;
    }
}

// ---------------- grand fused LN1 + FF1 + relu + FF2 + residual + LN2 (r16, unchanged) ----------------
__global__ __launch_bounds__(512) void ffln_kernel(
    const u16* __restrict__ At, const u16* __restrict__ xb,
    const float* __restrict__ g1, const float* __restrict__ be1,
    const u16* __restrict__ W1T, const float* __restrict__ b1,
    const u16* __restrict__ W2T, const float* __restrict__ b2,
    const float* __restrict__ g2, const float* __restrict__ be2,
    float* __restrict__ out)
{
    extern __shared__ char smem[];
    char* H    = smem;              // [64 rows][1024B], chunk16 ^ (row&7)
    char* F1   = smem + 65536;      // [64 rows][512B] (after FF1; FF1 bufB before that)
    char* BSTa = smem + 98304;      // 32KB weight staging buf A
    float* Ps = (float*)(smem + 131072);
    float* Pq = Ps + 128;

    const int tid = threadIdx.x, wave = tid >> 6, lane = tid & 63;
    const int lr = lane & 15, lg = lane >> 4, lr7 = lr & 7;
    const int r0 = blockIdx.x * 64;

    #pragma unroll
    for (int it = 0; it < 8; ++it) {
        int r = wave*8 + it;
        uint4 av = *(const uint4*)(At + (size_t)(r0 + r)*512 + lane*8);
        uint4 xv = *(const uint4*)(xb + (size_t)(r0 + r)*512 + lane*8);
        float v0 = bflo(av.x) + bflo(xv.x), v1 = bfhi(av.x) + bfhi(xv.x);
        float v2 = bflo(av.y) + bflo(xv.y), v3 = bfhi(av.y) + bfhi(xv.y);
        float v4 = bflo(av.z) + bflo(xv.z), v5 = bfhi(av.z) + bfhi(xv.z);
        float v6 = bflo(av.w) + bflo(xv.w), v7 = bfhi(av.w) + bfhi(xv.w);
        float s = ((v0+v1)+(v2+v3)) + ((v4+v5)+(v6+v7));
        float q = ((v0*v0+v1*v1)+(v2*v2+v3*v3)) + ((v4*v4+v5*v5)+(v6*v6+v7*v7));
        #pragma unroll
        for (int d = 1; d < 64; d <<= 1) { s += __shfl_xor(s, d); q += __shfl_xor(q, d); }
        float mu = s * (1.f/512.f);
        float rs = rsqrtf(q * (1.f/512.f) - mu*mu + 1e-5f);
        float4 gA = *(const float4*)(g1 + lane*8), gB = *(const float4*)(g1 + lane*8 + 4);
        float4 eA = *(const float4*)(be1 + lane*8), eB = *(const float4*)(be1 + lane*8 + 4);
        float h0 = (v0-mu)*rs*gA.x + eA.x, h1 = (v1-mu)*rs*gA.y + eA.y;
        float h2 = (v2-mu)*rs*gA.z + eA.z, h3 = (v3-mu)*rs*gA.w + eA.w;
        float h4 = (v4-mu)*rs*gB.x + eB.x, h5 = (v5-mu)*rs*gB.y + eB.y;
        float h6 = (v6-mu)*rs*gB.z + eB.z, h7 = (v7-mu)*rs*gB.w + eB.w;
        uint4 hw = make_uint4(cvt_pk_bf16(h0,h1), cvt_pk_bf16(h2,h3),
                              cvt_pk_bf16(h4,h5), cvt_pk_bf16(h6,h7));
        *(uint4*)(H + r*1024 + ((lane ^ (r & 7)) << 4)) = hw;
    }
    __syncthreads();

    const int wr = (wave & 3)*16, wcB = (wave >> 2)*128;

    auto stageW1 = [&](char* buf, int s8) {
        int k0 = s8*64;
        #pragma unroll
        for (int i = 0; i < 4; ++i) {
            int slot = i*512 + tid;
            int row = slot >> 3, ch = slot & 7;
            GLOAD16(W1T + (size_t)row*512 + k0 + ((ch ^ (row & 7)) << 3),
                    buf + i*8192 + wave*1024);
        }
    };
    stageW1(BSTa, 0);
    f32x4 acc1[8] = {};
    #pragma unroll
    for (int s8 = 0; s8 < 8; ++s8) {
        char* cur = (s8 & 1) ? F1 : BSTa;
        asm volatile("s_waitcnt vmcnt(0)" ::: "memory");
        __builtin_amdgcn_s_barrier();
        if (s8 + 1 < 8) stageW1((s8 & 1) ? BSTa : F1, s8 + 1);
        #pragma unroll
        for (int kk = 0; kk < 2; ++kk) {
            v8s af = *(const v8s*)(H + (wr + lr)*1024 + (((s8*8 + kk*4 + lg) ^ lr7) << 4));
            v8s bf[8];
            #pragma unroll
            for (int j = 0; j < 8; ++j)
                bf[j] = *(const v8s*)(cur + (wcB + j*16 + lr)*128 + ((((kk<<2)|lg) ^ lr7) << 4));
            #pragma unroll
            for (int j = 0; j < 8; ++j)
                acc1[j] = __builtin_amdgcn_mfma_f32_16x16x32_bf16(bf[j], af, acc1[j], 0, 0, 0);
        }
    }
    __syncthreads();

    {
        int row = wr + lr;
        #pragma unroll
        for (int j = 0; j < 8; ++j) {
            int col0 = wcB + j*16 + lg*4;
            float4 b4 = *(const float4*)(b1 + col0);
            float v0 = fmaxf(acc1[j][0] + b4.x, 0.f), v1 = fmaxf(acc1[j][1] + b4.y, 0.f);
            float v2 = fmaxf(acc1[j][2] + b4.z, 0.f), v3 = fmaxf(acc1[j][3] + b4.w, 0.f);
            *(uint2*)(F1 + row*512 + (((col0 >> 3) ^ (row & 7)) << 4) + (col0 & 7)*2)
                = make_uint2(cvt_pk_bf16(v0, v1), cvt_pk_bf16(v2, v3));
        }
    }

    const int row = wr + lr;
    uint2 hres[2][8];
    #pragma unroll
    for (int nh = 0; nh < 2; ++nh)
        #pragma unroll
        for (int j = 0; j < 8; ++j) {
            int col0 = nh*256 + wcB + j*16 + lg*4;
            hres[nh][j] = *(const uint2*)(H + row*1024 +
                            ((((col0 & 511) >> 3) ^ (row & 7)) << 4) + (col0 & 7)*2);
        }
    __syncthreads();

    auto stageW2 = [&](char* buf, int g) {
        int nh = g >> 2, k0 = (g & 3)*64;
        #pragma unroll
        for (int i = 0; i < 4; ++i) {
            int slot = i*512 + tid;
            int rw = slot >> 3, ch = slot & 7;
            GLOAD16(W2T + (size_t)(nh*256 + rw)*256 + k0 + ((ch ^ (rw & 7)) << 3),
                    buf + i*8192 + wave*1024);
        }
    };
    stageW2(H, 0);
    f32x4 acc2[2][8] = {};
    #pragma unroll
    for (int g = 0; g < 8; ++g) {
        char* cur = (g & 1) ? (H + 32768) : H;
        asm volatile("s_waitcnt vmcnt(0)" ::: "memory");
        __builtin_amdgcn_s_barrier();
        if (g + 1 < 8) stageW2((g & 1) ? H : (H + 32768), g + 1);
        const int nh = g >> 2, s4 = g & 3;
        #pragma unroll
        for (int kk = 0; kk < 2; ++kk) {
            v8s af = *(const v8s*)(F1 + (wr + lr)*512 + (((s4*8 + kk*4 + lg) ^ lr7) << 4));
            v8s bf[8];
            #pragma unroll
            for (int j = 0; j < 8; ++j)
                bf[j] = *(const v8s*)(cur + (wcB + j*16 + lr)*128 + ((((kk<<2)|lg) ^ lr7) << 4));
            #pragma unroll
            for (int j = 0; j < 8; ++j)
                acc2[nh][j] = __builtin_amdgcn_mfma_f32_16x16x32_bf16(bf[j], af, acc2[nh][j], 0, 0, 0);
        }
    }

    float s = 0.f, q = 0.f;
    #pragma unroll
    for (int nh = 0; nh < 2; ++nh) {
        #pragma unroll
        for (int j = 0; j < 8; ++j) {
            int col0 = nh*256 + wcB + j*16 + lg*4;
            float4 b4 = *(const float4*)(b2 + col0);
            uint2 hh = hres[nh][j];
            f32x4 a = acc2[nh][j];
            a[0] += b4.x + bflo(hh.x); a[1] += b4.y + bfhi(hh.x);
            a[2] += b4.z + bflo(hh.y); a[3] += b4.w + bfhi(hh.y);
            acc2[nh][j] = a;
            s += (a[0]+a[1]) + (a[2]+a[3]);
            q += (a[0]*a[0]+a[1]*a[1]) + (a[2]*a[2]+a[3]*a[3]);
        }
    }
    s += __shfl_xor(s, 16); s += __shfl_xor(s, 32);
    q += __shfl_xor(q, 16); q += __shfl_xor(q, 32);
    __syncthreads();
    if (lg == 0) { Ps[row*2 + (wave >> 2)] = s; Pq[row*2 + (wave >> 2)] = q; }
    __syncthreads();
    float st = Ps[row*2] + Ps[row*2 + 1];
    float qt = Pq[row*2] + Pq[row*2 + 1];
    float mu = st * (1.f/512.f);
    float rs = rsqrtf(qt * (1.f/512.f) - mu*mu + 1e-5f);

    #pragma unroll
    for (int nh = 0; nh < 2; ++nh) {
        #pragma unroll
        for (int j = 0; j < 8; ++j) {
            int col0 = nh*256 + wcB + j*16 + lg*4;
            float4 gg = *(const float4*)(g2 + col0);
            float4 ee = *(const float4*)(be2 + col0);
            f32x4 a = acc2[nh][j];
            float4 o;
            o.x = (a[0]-mu)*rs*gg.x + ee.x;
            o.y = (a[1]-mu)*rs*gg.y + ee.y;
            o.z = (a[2]-mu)*rs*gg.z + ee.z;
            o.w = (a[3]-mu)*rs*gg.w + ee.w;
            *(float4*)(out + (size_t)(r0 + row)*512 + col0) = o;
        }
    }
}

// ---------------- launcher ----------------

extern "C" void kernel_launch(void* const* d_in, const int* in_sizes, int n_in,
                              void* d_out, int out_size, void* d_ws, size_t ws_size,
                              hipStream_t stream)
{
    const float* x   = (const float*)d_in[0];
    const float* Wq  = (const float*)d_in[1];
    const float* bq  = (const float*)d_in[2];
    const float* Wk  = (const float*)d_in[3];
    const float* bk  = (const float*)d_in[4];
    const float* Wv  = (const float*)d_in[5];
    const float* bv  = (const float*)d_in[6];
    const float* W1  = (const float*)d_in[7];
    const float* bf1 = (const float*)d_in[8];
    const float* W2  = (const float*)d_in[9];
    const float* bf2 = (const float*)d_in[10];
    const float* g1  = (const float*)d_in[11];
    const float* be1 = (const float*)d_in[12];
    const float* g2  = (const float*)d_in[13];
    const float* be2 = (const float*)d_in[14];

    char* ws = (char*)d_ws;
    const size_t MB = 1ull << 20;
    const size_t KB = 1024;
    u16* xb    = (u16*)(ws + 0);          // x bf16 linear — live through ffln
    u16* xp    = (u16*)(ws + 16*MB);      // x packed fragments
    u16* attnb = (u16*)(ws + 32*MB);      // attention output
    u16* Wp    = (u16*)(ws + 48*MB);                 // Wqkv packed [96][64][16][8]
    u16* W1T   = (u16*)(ws + 48*MB + 1536*KB);       // [256][512]
    u16* W2T   = (u16*)(ws + 48*MB + 1792*KB);       // [512][256]
    (void)ws_size; (void)in_sizes; (void)n_in; (void)out_size;

    cvt_all_kernel<<<11520, 256, 0, stream>>>(x, xb, xp, Wq, Wk, Wv, W1, W2, Wp, W1T, W2T);

    fused_attn_kernel<<<256, 512, 131072, stream>>>(xp, Wp, bq, bk, bv, attnb);

    ffln_kernel<<<256, 512, 132096, stream>>>(attnb, xb, g1, be1, W1T, bf1, W2T, bf2,
                                              g2, be2, (float*)d_out);
}

// Round 18
// 115.140 us; speedup vs baseline: 1.1929x; 1.1929x over previous
//
#include <hip/hip_runtime.h>

#define BS 32
#define NE 512
#define DMODEL 512
#define HEADS 8
#define EMB 64
#define FFH 256
#define MTOK (BS*NE)   // 16384

typedef unsigned short u16;
typedef short v8s __attribute__((ext_vector_type(8)));
typedef float f32x4 __attribute__((ext_vector_type(4)));
typedef u16 u16x4 __attribute__((ext_vector_type(4)));

#define GLOAD16(G, L) \
  __builtin_amdgcn_global_load_lds((const __attribute__((address_space(1))) unsigned int*)(G), \
      (__attribute__((address_space(3))) unsigned int*)(L), 16, 0, 0)

static __device__ __forceinline__ unsigned cvt_pk_bf16(float lo, float hi) {
    unsigned r;
    asm("v_cvt_pk_bf16_f32 %0, %1, %2" : "=v"(r) : "v"(lo), "v"(hi));
    return r;
}

static __device__ __forceinline__ u16 f2bf_bits(float f) {
    unsigned u = __float_as_uint(f);
    u += 0x7fffu + ((u >> 16) & 1u);   // round-to-nearest-even
    return (u16)(u >> 16);
}
static __device__ __forceinline__ float bflo(unsigned w) { return __uint_as_float(w << 16); }
static __device__ __forceinline__ float bfhi(unsigned w) { return __uint_as_float(w & 0xffff0000u); }

// ---------------- fused conversion ----------------
// id<8192: x -> xb linear + xp packed [tok16][k8][16][8].
// 8192..11263: Wq/Wk/Wv -> Wp packed (row = output col 0..1535).
// 11264..11519: W1/W2 -> row-major transposed via LDS 32x32 tiles.
__global__ __launch_bounds__(256) void cvt_all_kernel(
    const float* __restrict__ x, u16* __restrict__ xb, u16* __restrict__ xp,
    const float* __restrict__ Wq, const float* __restrict__ Wk, const float* __restrict__ Wv,
    const float* __restrict__ W1, const float* __restrict__ W2,
    u16* __restrict__ Wp, u16* __restrict__ W1T, u16* __restrict__ W2T)
{
    const int id = blockIdx.x;
    const int tt = threadIdx.x;
    if (id < 8192) {
        int i = id*256 + tt;
        float4 v = ((const float4*)x)[i];
        u16x4 o = { f2bf_bits(v.x), f2bf_bits(v.y), f2bf_bits(v.z), f2bf_bits(v.w) };
        ((u16x4*)xb)[i] = o;
        int e = i * 4;
        int row = e >> 9, k = e & 511;
        *(u16x4*)(xp + ((size_t)(row >> 4)*64 + (k >> 3))*128 + (row & 15)*8 + (k & 7)) = o;
        return;
    }
    if (id < 11264) {                  // Wqkv -> packed
        int widx = (id - 8192)*256 + tt;   // 0..786431
        int w = widx >> 18, rem = widx & 262143;
        int k = rem >> 9, n = rem & 511;
        const float* src = (w == 0) ? Wq : (w == 1) ? Wk : Wv;
        int np = w*512 + n;
        Wp[((size_t)(np >> 4)*64 + (k >> 3))*128 + (np & 15)*8 + (k & 7)] = f2bf_bits(src[rem]);
        return;
    }
    __shared__ float T[32][33];
    const int t2 = id - 11264;         // 0..255
    const float* src; u16* dst; int ldsrc, lddst, sr, sc;
    if (t2 < 128) {                    // W1: 512x256, 16x8 tiles
        int tr = t2 >> 3, tc = t2 & 7;
        src = W1; ldsrc = 256; sr = tr*32; sc = tc*32;
        dst = W1T + (size_t)sc*512 + sr; lddst = 512;
    } else {                           // W2: 256x512, 8x16 tiles
        int t = t2 - 128;
        int tr = t >> 4, tc = t & 15;
        src = W2; ldsrc = 512; sr = tr*32; sc = tc*32;
        dst = W2T + (size_t)sc*256 + sr; lddst = 256;
    }
    {
        int r = tt >> 3, c4 = (tt & 7) << 2;
        float4 v = *(const float4*)(src + (size_t)(sr + r)*ldsrc + sc + c4);
        T[r][c4] = v.x; T[r][c4+1] = v.y; T[r][c4+2] = v.z; T[r][c4+3] = v.w;
    }
    __syncthreads();
    {
        int n = tt >> 3, k4 = (tt & 7) << 2;
        u16x4 o = { f2bf_bits(T[k4][n]), f2bf_bits(T[k4+1][n]),
                    f2bf_bits(T[k4+2][n]), f2bf_bits(T[k4+3][n]) };
        *(u16x4*)(dst + (size_t)n*lddst + k4) = o;
    }
}

// ---------------- fused QKV + attention: 1 block = 1 (b,h), 512 thr / 8 waves ----------------
// XCD-aware decode: all 8 heads of batch b share id%8 residue -> same XCD L2 serves
// the 512KB x-slice for all of them (fixes r17's 197MB HBM re-fetch).
__global__ __launch_bounds__(512) void fused_attn_kernel(
    const u16* __restrict__ xp, const u16* __restrict__ Wp,
    const float* __restrict__ bsQ, const float* __restrict__ bsK, const float* __restrict__ bsV,
    u16* __restrict__ O)
{
    extern __shared__ char smem[];
    const int id = blockIdx.x;
    const int xcd = id & 7, slot = id >> 3;
    const int b = xcd*4 + (slot & 3), h = slot >> 2;
    const int tid = threadIdx.x, wave = tid >> 6, lane = tid & 63;
    const int lr = lane & 15, lg = lane >> 4, lr7 = lr & 7;
    char* Bnc = smem + 65536;
    const float SCL = 0.18033688011112042f;   // 0.125*log2(e)

    // fragment base pointers (u16 units): frag(i, K32-step s) = base + i*8192 + s*512
    const u16* a0  = xp + ((size_t)(b*32 + wave*4)*64 + lg)*128 + lr*8;
    const u16* bq0 = Wp + ((size_t)(h*4      )*64 + lg)*128 + lr*8;
    const u16* bk0 = Wp + ((size_t)(32 + h*4 )*64 + lg)*128 + lr*8;
    const u16* bv0 = Wp + ((size_t)(64 + h*4 )*64 + lg)*128 + lr*8;

    f32x4 acc[4][4];

    auto run_pass = [&](const u16* bb, bool swap) {
        #pragma unroll
        for (int i = 0; i < 4; ++i)
            #pragma unroll
            for (int j = 0; j < 4; ++j) acc[i][j] = f32x4{0.f,0.f,0.f,0.f};
        v8s afA[4], bfA[4], afB[4], bfB[4];
        #pragma unroll
        for (int i = 0; i < 4; ++i) { afA[i] = *(const v8s*)(a0 + i*8192); bfA[i] = *(const v8s*)(bb + i*8192); }
        #pragma unroll
        for (int tp = 0; tp < 8; ++tp) {
            #pragma unroll
            for (int i = 0; i < 4; ++i) {
                afB[i] = *(const v8s*)(a0 + (2*tp + 1)*512 + i*8192);
                bfB[i] = *(const v8s*)(bb + (2*tp + 1)*512 + i*8192);
            }
            #pragma unroll
            for (int i = 0; i < 4; ++i)
                #pragma unroll
                for (int j = 0; j < 4; ++j)
                    acc[i][j] = swap
                        ? __builtin_amdgcn_mfma_f32_16x16x32_bf16(bfA[j], afA[i], acc[i][j], 0, 0, 0)
                        : __builtin_amdgcn_mfma_f32_16x16x32_bf16(afA[i], bfA[j], acc[i][j], 0, 0, 0);
            if (tp < 7) {
                #pragma unroll
                for (int i = 0; i < 4; ++i) {
                    afA[i] = *(const v8s*)(a0 + (2*tp + 2)*512 + i*8192);
                    bfA[i] = *(const v8s*)(bb + (2*tp + 2)*512 + i*8192);
                }
            }
            #pragma unroll
            for (int i = 0; i < 4; ++i)
                #pragma unroll
                for (int j = 0; j < 4; ++j)
                    acc[i][j] = swap
                        ? __builtin_amdgcn_mfma_f32_16x16x32_bf16(bfB[j], afB[i], acc[i][j], 0, 0, 0)
                        : __builtin_amdgcn_mfma_f32_16x16x32_bf16(afB[i], bfB[j], acc[i][j], 0, 0, 0);
        }
    };

    // ---- q pass: swapped acc; lane: tok = wave*64+i*16+lr, d = j*16+lg*4+{0..3} ----
    run_pass(bq0, true);
    #pragma unroll
    for (int j = 0; j < 4; ++j) {
        float4 b4 = *(const float4*)(bsQ + h*64 + j*16 + lg*4);
        #pragma unroll
        for (int i = 0; i < 4; ++i) {
            int tok = wave*64 + i*16 + lr;
            float v0 = (acc[i][j][0] + b4.x)*SCL, v1 = (acc[i][j][1] + b4.y)*SCL;
            float v2 = (acc[i][j][2] + b4.z)*SCL, v3 = (acc[i][j][3] + b4.w)*SCL;
            int chunk = 2*j + (lg >> 1);
            *(uint2*)(Bnc + tok*128 + ((chunk ^ lr7) << 4) + (lg & 1)*8)
                = make_uint2(cvt_pk_bf16(v0, v1), cvt_pk_bf16(v2, v3));
        }
    }
    v8s qa[4][2];
    #pragma unroll
    for (int ti = 0; ti < 4; ++ti) {
        const char* qr = Bnc + (wave*64 + ti*16 + lr)*128;
        qa[ti][0] = *(const v8s*)(qr + ((lg ^ lr7) << 4));
        qa[ti][1] = *(const v8s*)(qr + (((4 | lg) ^ lr7) << 4));
    }

    // ---- k pass: swapped acc -> K_lds ----
    run_pass(bk0, true);
    #pragma unroll
    for (int j = 0; j < 4; ++j) {
        float4 b4 = *(const float4*)(bsK + h*64 + j*16 + lg*4);
        #pragma unroll
        for (int i = 0; i < 4; ++i) {
            int tok = wave*64 + i*16 + lr;
            float v0 = acc[i][j][0] + b4.x, v1 = acc[i][j][1] + b4.y;
            float v2 = acc[i][j][2] + b4.z, v3 = acc[i][j][3] + b4.w;
            int chunk = 2*j + (lg >> 1);
            *(uint2*)(smem + tok*128 + ((chunk ^ lr7) << 4) + (lg & 1)*8)
                = make_uint2(cvt_pk_bf16(v0, v1), cvt_pk_bf16(v2, v3));
        }
    }
    __syncthreads();   // all qa reads done + K visible

    // ---- v pass: normal acc; lane: d = j*16+lr, toks = wave*64+i*16+lg*4+{0..3} ----
    run_pass(bv0, false);
    #pragma unroll
    for (int j = 0; j < 4; ++j) {
        #pragma unroll
        for (int i = 0; i < 4; ++i) {
            int d = j*16 + lr;
            float bv = bsV[h*64 + d];
            int chunk = wave*8 + 2*i + (lg >> 1);
            *(uint2*)(Bnc + d*1024 + ((chunk ^ lr7) << 4) + (lg & 1)*8)
                = make_uint2(cvt_pk_bf16(acc[i][j][0] + bv, acc[i][j][1] + bv),
                             cvt_pk_bf16(acc[i][j][2] + bv, acc[i][j][3] + bv));
        }
    }
    __syncthreads();   // VT ready

    // ---- attention core ----
    const int q0 = wave*64;
    f32x4 o[4][4] = {};
    float ssum[4] = {0.f, 0.f, 0.f, 0.f};

    #pragma unroll 1
    for (int c = 0; c < 16; ++c) {
        const char* kr0 = (const char*)smem + ((2*c  )*16 + lr)*128;
        const char* kr1 = (const char*)smem + ((2*c+1)*16 + lr)*128;
        v8s kA0 = *(const v8s*)(kr0 + ((lg ^ lr7) << 4));
        v8s kA1 = *(const v8s*)(kr0 + (((4|lg) ^ lr7) << 4));
        v8s kB0 = *(const v8s*)(kr1 + ((lg ^ lr7) << 4));
        v8s kB1 = *(const v8s*)(kr1 + (((4|lg) ^ lr7) << 4));
        v8s vf[4];
        #pragma unroll
        for (int dt = 0; dt < 4; ++dt) {
            const char* vr = Bnc + (dt*16 + lr)*1024;
            int c0 = c*4 + (lg >> 1), rem = (lg & 1)*8;
            uint2 lo = *(const uint2*)(vr + (((c0    ) ^ lr7) << 4) + rem);
            uint2 hi = *(const uint2*)(vr + (((c0 + 2) ^ lr7) << 4) + rem);
            uint4 u = make_uint4(lo.x, lo.y, hi.x, hi.y);
            vf[dt] = *(v8s*)&u;
        }
        #pragma unroll
        for (int ti = 0; ti < 4; ++ti) {
            __builtin_amdgcn_s_setprio(1);
            f32x4 s0 = {0.f,0.f,0.f,0.f}, s1 = {0.f,0.f,0.f,0.f};
            s0 = __builtin_amdgcn_mfma_f32_16x16x32_bf16(kA0, qa[ti][0], s0, 0, 0, 0);
            s0 = __builtin_amdgcn_mfma_f32_16x16x32_bf16(kA1, qa[ti][1], s0, 0, 0, 0);
            s1 = __builtin_amdgcn_mfma_f32_16x16x32_bf16(kB0, qa[ti][0], s1, 0, 0, 0);
            s1 = __builtin_amdgcn_mfma_f32_16x16x32_bf16(kB1, qa[ti][1], s1, 0, 0, 0);
            __builtin_amdgcn_s_setprio(0);
            float p0 = exp2f(s0[0]), p1 = exp2f(s0[1]), p2 = exp2f(s0[2]), p3 = exp2f(s0[3]);
            float r0 = exp2f(s1[0]), r1 = exp2f(s1[1]), r2 = exp2f(s1[2]), r3 = exp2f(s1[3]);
            ssum[ti] += ((p0 + p1) + (p2 + p3)) + ((r0 + r1) + (r2 + r3));
            unsigned a0w = cvt_pk_bf16(p0, p1), a1w = cvt_pk_bf16(p2, p3);
            unsigned b0w = cvt_pk_bf16(r0, r1), b1w = cvt_pk_bf16(r2, r3);
            uint4 pu = make_uint4(a0w, a1w, b0w, b1w);
            v8s pb = *(v8s*)&pu;
            __builtin_amdgcn_s_setprio(1);
            #pragma unroll
            for (int dt = 0; dt < 4; ++dt)
                o[ti][dt] = __builtin_amdgcn_mfma_f32_16x16x32_bf16(vf[dt], pb, o[ti][dt], 0, 0, 0);
            __builtin_amdgcn_s_setprio(0);
        }
    }

    __syncthreads();   // K/VT dead; LDS reused for O transpose

    float rinv[4];
    #pragma unroll
    for (int ti = 0; ti < 4; ++ti) {
        float v = ssum[ti];
        v += __shfl_xor(v, 16);
        v += __shfl_xor(v, 32);
        rinv[ti] = 1.f / v;
    }

    char* ow = (char*)smem + wave*10240;
    #pragma unroll
    for (int ti = 0; ti < 4; ++ti) {
        #pragma unroll
        for (int dt = 0; dt < 4; ++dt) {
            unsigned d0 = cvt_pk_bf16(o[ti][dt][0]*rinv[ti], o[ti][dt][1]*rinv[ti]);
            unsigned d1 = cvt_pk_bf16(o[ti][dt][2]*rinv[ti], o[ti][dt][3]*rinv[ti]);
            *(uint2*)(ow + (ti*16 + lr)*160 + dt*32 + lg*8) = make_uint2(d0, d1);
        }
    }
    __asm__ volatile("s_waitcnt lgkmcnt(0)" ::: "memory");
    #pragma unroll
    for (int it = 0; it < 8; ++it) {
        int rr2 = it*8 + (lane >> 3);
        uint4 v = *(const uint4*)(ow + rr2*160 + (lane & 7)*16);
        *(uint4*)(O + (size_t)(b*NE + q0 + rr2)*DMODEL + h*EMB + (lane & 7)*8) = v;
    }
}

// ---------------- grand fused LN1 + FF1 + relu + FF2 + residual + LN2 (r16, unchanged) ----------------
__global__ __launch_bounds__(512) void ffln_kernel(
    const u16* __restrict__ At, const u16* __restrict__ xb,
    const float* __restrict__ g1, const float* __restrict__ be1,
    const u16* __restrict__ W1T, const float* __restrict__ b1,
    const u16* __restrict__ W2T, const float* __restrict__ b2,
    const float* __restrict__ g2, const float* __restrict__ be2,
    float* __restrict__ out)
{
    extern __shared__ char smem[];
    char* H    = smem;
    char* F1   = smem + 65536;
    char* BSTa = smem + 98304;
    float* Ps = (float*)(smem + 131072);
    float* Pq = Ps + 128;

    const int tid = threadIdx.x, wave = tid >> 6, lane = tid & 63;
    const int lr = lane & 15, lg = lane >> 4, lr7 = lr & 7;
    const int r0 = blockIdx.x * 64;

    #pragma unroll
    for (int it = 0; it < 8; ++it) {
        int r = wave*8 + it;
        uint4 av = *(const uint4*)(At + (size_t)(r0 + r)*512 + lane*8);
        uint4 xv = *(const uint4*)(xb + (size_t)(r0 + r)*512 + lane*8);
        float v0 = bflo(av.x) + bflo(xv.x), v1 = bfhi(av.x) + bfhi(xv.x);
        float v2 = bflo(av.y) + bflo(xv.y), v3 = bfhi(av.y) + bfhi(xv.y);
        float v4 = bflo(av.z) + bflo(xv.z), v5 = bfhi(av.z) + bfhi(xv.z);
        float v6 = bflo(av.w) + bflo(xv.w), v7 = bfhi(av.w) + bfhi(xv.w);
        float s = ((v0+v1)+(v2+v3)) + ((v4+v5)+(v6+v7));
        float q = ((v0*v0+v1*v1)+(v2*v2+v3*v3)) + ((v4*v4+v5*v5)+(v6*v6+v7*v7));
        #pragma unroll
        for (int d = 1; d < 64; d <<= 1) { s += __shfl_xor(s, d); q += __shfl_xor(q, d); }
        float mu = s * (1.f/512.f);
        float rs = rsqrtf(q * (1.f/512.f) - mu*mu + 1e-5f);
        float4 gA = *(const float4*)(g1 + lane*8), gB = *(const float4*)(g1 + lane*8 + 4);
        float4 eA = *(const float4*)(be1 + lane*8), eB = *(const float4*)(be1 + lane*8 + 4);
        float h0 = (v0-mu)*rs*gA.x + eA.x, h1 = (v1-mu)*rs*gA.y + eA.y;
        float h2 = (v2-mu)*rs*gA.z + eA.z, h3 = (v3-mu)*rs*gA.w + eA.w;
        float h4 = (v4-mu)*rs*gB.x + eB.x, h5 = (v5-mu)*rs*gB.y + eB.y;
        float h6 = (v6-mu)*rs*gB.z + eB.z, h7 = (v7-mu)*rs*gB.w + eB.w;
        uint4 hw = make_uint4(cvt_pk_bf16(h0,h1), cvt_pk_bf16(h2,h3),
                              cvt_pk_bf16(h4,h5), cvt_pk_bf16(h6,h7));
        *(uint4*)(H + r*1024 + ((lane ^ (r & 7)) << 4)) = hw;
    }
    __syncthreads();

    const int wr = (wave & 3)*16, wcB = (wave >> 2)*128;

    auto stageW1 = [&](char* buf, int s8) {
        int k0 = s8*64;
        #pragma unroll
        for (int i = 0; i < 4; ++i) {
            int slot = i*512 + tid;
            int row = slot >> 3, ch = slot & 7;
            GLOAD16(W1T + (size_t)row*512 + k0 + ((ch ^ (row & 7)) << 3),
                    buf + i*8192 + wave*1024);
        }
    };
    stageW1(BSTa, 0);
    f32x4 acc1[8] = {};
    #pragma unroll
    for (int s8 = 0; s8 < 8; ++s8) {
        char* cur = (s8 & 1) ? F1 : BSTa;
        asm volatile("s_waitcnt vmcnt(0)" ::: "memory");
        __builtin_amdgcn_s_barrier();
        if (s8 + 1 < 8) stageW1((s8 & 1) ? BSTa : F1, s8 + 1);
        #pragma unroll
        for (int kk = 0; kk < 2; ++kk) {
            v8s af = *(const v8s*)(H + (wr + lr)*1024 + (((s8*8 + kk*4 + lg) ^ lr7) << 4));
            v8s bf[8];
            #pragma unroll
            for (int j = 0; j < 8; ++j)
                bf[j] = *(const v8s*)(cur + (wcB + j*16 + lr)*128 + ((((kk<<2)|lg) ^ lr7) << 4));
            #pragma unroll
            for (int j = 0; j < 8; ++j)
                acc1[j] = __builtin_amdgcn_mfma_f32_16x16x32_bf16(bf[j], af, acc1[j], 0, 0, 0);
        }
    }
    __syncthreads();

    {
        int row = wr + lr;
        #pragma unroll
        for (int j = 0; j < 8; ++j) {
            int col0 = wcB + j*16 + lg*4;
            float4 b4 = *(const float4*)(b1 + col0);
            float v0 = fmaxf(acc1[j][0] + b4.x, 0.f), v1 = fmaxf(acc1[j][1] + b4.y, 0.f);
            float v2 = fmaxf(acc1[j][2] + b4.z, 0.f), v3 = fmaxf(acc1[j][3] + b4.w, 0.f);
            *(uint2*)(F1 + row*512 + (((col0 >> 3) ^ (row & 7)) << 4) + (col0 & 7)*2)
                = make_uint2(cvt_pk_bf16(v0, v1), cvt_pk_bf16(v2, v3));
        }
    }

    const int row = wr + lr;
    uint2 hres[2][8];
    #pragma unroll
    for (int nh = 0; nh < 2; ++nh)
        #pragma unroll
        for (int j = 0; j < 8; ++j) {
            int col0 = nh*256 + wcB + j*16 + lg*4;
            hres[nh][j] = *(const uint2*)(H + row*1024 +
                            ((((col0 & 511) >> 3) ^ (row & 7)) << 4) + (col0 & 7)*2);
        }
    __syncthreads();

    auto stageW2 = [&](char* buf, int g) {
        int nh = g >> 2, k0 = (g & 3)*64;
        #pragma unroll
        for (int i = 0; i < 4; ++i) {
            int slot = i*512 + tid;
            int rw = slot >> 3, ch = slot & 7;
            GLOAD16(W2T + (size_t)(nh*256 + rw)*256 + k0 + ((ch ^ (rw & 7)) << 3),
                    buf + i*8192 + wave*1024);
        }
    };
    stageW2(H, 0);
    f32x4 acc2[2][8] = {};
    #pragma unroll
    for (int g = 0; g < 8; ++g) {
        char* cur = (g & 1) ? (H + 32768) : H;
        asm volatile("s_waitcnt vmcnt(0)" ::: "memory");
        __builtin_amdgcn_s_barrier();
        if (g + 1 < 8) stageW2((g & 1) ? H : (H + 32768), g + 1);
        const int nh = g >> 2, s4 = g & 3;
        #pragma unroll
        for (int kk = 0; kk < 2; ++kk) {
            v8s af = *(const v8s*)(F1 + (wr + lr)*512 + (((s4*8 + kk*4 + lg) ^ lr7) << 4));
            v8s bf[8];
            #pragma unroll
            for (int j = 0; j < 8; ++j)
                bf[j] = *(const v8s*)(cur + (wcB + j*16 + lr)*128 + ((((kk<<2)|lg) ^ lr7) << 4));
            #pragma unroll
            for (int j = 0; j < 8; ++j)
                acc2[nh][j] = __builtin_amdgcn_mfma_f32_16x16x32_bf16(bf[j], af, acc2[nh][j], 0, 0, 0);
        }
    }

    float s = 0.f, q = 0.f;
    #pragma unroll
    for (int nh = 0; nh < 2; ++nh) {
        #pragma unroll
        for (int j = 0; j < 8; ++j) {
            int col0 = nh*256 + wcB + j*16 + lg*4;
            float4 b4 = *(const float4*)(b2 + col0);
            uint2 hh = hres[nh][j];
            f32x4 a = acc2[nh][j];
            a[0] += b4.x + bflo(hh.x); a[1] += b4.y + bfhi(hh.x);
            a[2] += b4.z + bflo(hh.y); a[3] += b4.w + bfhi(hh.y);
            acc2[nh][j] = a;
            s += (a[0]+a[1]) + (a[2]+a[3]);
            q += (a[0]*a[0]+a[1]*a[1]) + (a[2]*a[2]+a[3]*a[3]);
        }
    }
    s += __shfl_xor(s, 16); s += __shfl_xor(s, 32);
    q += __shfl_xor(q, 16); q += __shfl_xor(q, 32);
    __syncthreads();
    if (lg == 0) { Ps[row*2 + (wave >> 2)] = s; Pq[row*2 + (wave >> 2)] = q; }
    __syncthreads();
    float st = Ps[row*2] + Ps[row*2 + 1];
    float qt = Pq[row*2] + Pq[row*2 + 1];
    float mu = st * (1.f/512.f);
    float rs = rsqrtf(qt * (1.f/512.f) - mu*mu + 1e-5f);

    #pragma unroll
    for (int nh = 0; nh < 2; ++nh) {
        #pragma unroll
        for (int j = 0; j < 8; ++j) {
            int col0 = nh*256 + wcB + j*16 + lg*4;
            float4 gg = *(const float4*)(g2 + col0);
            float4 ee = *(const float4*)(be2 + col0);
            f32x4 a = acc2[nh][j];
            float4 o;
            o.x = (a[0]-mu)*rs*gg.x + ee.x;
            o.y = (a[1]-mu)*rs*gg.y + ee.y;
            o.z = (a[2]-mu)*rs*gg.z + ee.z;
            o.w = (a[3]-mu)*rs*gg.w + ee.w;
            *(float4*)(out + (size_t)(r0 + row)*512 + col0) = o;
        }
    }
}

// ---------------- launcher ----------------

extern "C" void kernel_launch(void* const* d_in, const int* in_sizes, int n_in,
                              void* d_out, int out_size, void* d_ws, size_t ws_size,
                              hipStream_t stream)
{
    const float* x   = (const float*)d_in[0];
    const float* Wq  = (const float*)d_in[1];
    const float* bq  = (const float*)d_in[2];
    const float* Wk  = (const float*)d_in[3];
    const float* bk  = (const float*)d_in[4];
    const float* Wv  = (const float*)d_in[5];
    const float* bv  = (const float*)d_in[6];
    const float* W1  = (const float*)d_in[7];
    const float* bf1 = (const float*)d_in[8];
    const float* W2  = (const float*)d_in[9];
    const float* bf2 = (const float*)d_in[10];
    const float* g1  = (const float*)d_in[11];
    const float* be1 = (const float*)d_in[12];
    const float* g2  = (const float*)d_in[13];
    const float* be2 = (const float*)d_in[14];

    char* ws = (char*)d_ws;
    const size_t MB = 1ull << 20;
    const size_t KB = 1024;
    u16* xb    = (u16*)(ws + 0);          // x bf16 linear — live through ffln
    u16* xp    = (u16*)(ws + 16*MB);      // x packed fragments
    u16* attnb = (u16*)(ws + 32*MB);      // attention output
    u16* Wp    = (u16*)(ws + 48*MB);                 // Wqkv packed [96][64][16][8]
    u16* W1T   = (u16*)(ws + 48*MB + 1536*KB);       // [256][512]
    u16* W2T   = (u16*)(ws + 48*MB + 1792*KB);       // [512][256]
    (void)ws_size; (void)in_sizes; (void)n_in; (void)out_size;

    cvt_all_kernel<<<11520, 256, 0, stream>>>(x, xb, xp, Wq, Wk, Wv, W1, W2, Wp, W1T, W2T);

    fused_attn_kernel<<<256, 512, 131072, stream>>>(xp, Wp, bq, bk, bv, attnb);

    ffln_kernel<<<256, 512, 132096, stream>>>(attnb, xb, g1, be1, W1T, bf1, W2T, bf2,
                                              g2, be2, (float*)d_out);
}

// Round 19
// 112.464 us; speedup vs baseline: 1.2213x; 1.0238x over previous
//
#include <hip/hip_runtime.h>

#define BS 32
#define NE 512
#define DMODEL 512
#define HEADS 8
#define EMB 64
#define FFH 256
#define MTOK (BS*NE)   // 16384

typedef unsigned short u16;
typedef short v8s __attribute__((ext_vector_type(8)));
typedef float f32x4 __attribute__((ext_vector_type(4)));
typedef u16 u16x4 __attribute__((ext_vector_type(4)));

#define GLOAD16(G, L) \
  __builtin_amdgcn_global_load_lds((const __attribute__((address_space(1))) unsigned int*)(G), \
      (__attribute__((address_space(3))) unsigned int*)(L), 16, 0, 0)

static __device__ __forceinline__ unsigned cvt_pk_bf16(float lo, float hi) {
    unsigned r;
    asm("v_cvt_pk_bf16_f32 %0, %1, %2" : "=v"(r) : "v"(lo), "v"(hi));
    return r;
}

static __device__ __forceinline__ u16 f2bf_bits(float f) {
    unsigned u = __float_as_uint(f);
    u += 0x7fffu + ((u >> 16) & 1u);   // round-to-nearest-even
    return (u16)(u >> 16);
}
static __device__ __forceinline__ float bflo(unsigned w) { return __uint_as_float(w << 16); }
static __device__ __forceinline__ float bfhi(unsigned w) { return __uint_as_float(w & 0xffff0000u); }

// ---------------- fused conversion (r18, unchanged) ----------------
__global__ __launch_bounds__(256) void cvt_all_kernel(
    const float* __restrict__ x, u16* __restrict__ xb, u16* __restrict__ xp,
    const float* __restrict__ Wq, const float* __restrict__ Wk, const float* __restrict__ Wv,
    const float* __restrict__ W1, const float* __restrict__ W2,
    u16* __restrict__ Wp, u16* __restrict__ W1T, u16* __restrict__ W2T)
{
    const int id = blockIdx.x;
    const int tt = threadIdx.x;
    if (id < 8192) {
        int i = id*256 + tt;
        float4 v = ((const float4*)x)[i];
        u16x4 o = { f2bf_bits(v.x), f2bf_bits(v.y), f2bf_bits(v.z), f2bf_bits(v.w) };
        ((u16x4*)xb)[i] = o;
        int e = i * 4;
        int row = e >> 9, k = e & 511;
        *(u16x4*)(xp + ((size_t)(row >> 4)*64 + (k >> 3))*128 + (row & 15)*8 + (k & 7)) = o;
        return;
    }
    if (id < 11264) {                  // Wqkv -> packed
        int widx = (id - 8192)*256 + tt;   // 0..786431
        int w = widx >> 18, rem = widx & 262143;
        int k = rem >> 9, n = rem & 511;
        const float* src = (w == 0) ? Wq : (w == 1) ? Wk : Wv;
        int np = w*512 + n;
        Wp[((size_t)(np >> 4)*64 + (k >> 3))*128 + (np & 15)*8 + (k & 7)] = f2bf_bits(src[rem]);
        return;
    }
    __shared__ float T[32][33];
    const int t2 = id - 11264;         // 0..255
    const float* src; u16* dst; int ldsrc, lddst, sr, sc;
    if (t2 < 128) {                    // W1: 512x256, 16x8 tiles
        int tr = t2 >> 3, tc = t2 & 7;
        src = W1; ldsrc = 256; sr = tr*32; sc = tc*32;
        dst = W1T + (size_t)sc*512 + sr; lddst = 512;
    } else {                           // W2: 256x512, 8x16 tiles
        int t = t2 - 128;
        int tr = t >> 4, tc = t & 15;
        src = W2; ldsrc = 512; sr = tr*32; sc = tc*32;
        dst = W2T + (size_t)sc*256 + sr; lddst = 256;
    }
    {
        int r = tt >> 3, c4 = (tt & 7) << 2;
        float4 v = *(const float4*)(src + (size_t)(sr + r)*ldsrc + sc + c4);
        T[r][c4] = v.x; T[r][c4+1] = v.y; T[r][c4+2] = v.z; T[r][c4+3] = v.w;
    }
    __syncthreads();
    {
        int n = tt >> 3, k4 = (tt & 7) << 2;
        u16x4 o = { f2bf_bits(T[k4][n]), f2bf_bits(T[k4+1][n]),
                    f2bf_bits(T[k4+2][n]), f2bf_bits(T[k4+3][n]) };
        *(u16x4*)(dst + (size_t)n*lddst + k4) = o;
    }
}

// ---------------- fused QKV + attention: 1 block = 1 (b,h), 1024 thr / 16 waves ----------------
// 4 waves/SIMD (vs r18's 2) to hide the streaming-load and softmax-chain latency.
// Each wave owns 32 tokens: passes acc[2][4], attn core 2 q-subtiles.
// XCD-aware decode: all 8 heads of batch-group share id%8 residue.
__global__ __launch_bounds__(1024) void fused_attn_kernel(
    const u16* __restrict__ xp, const u16* __restrict__ Wp,
    const float* __restrict__ bsQ, const float* __restrict__ bsK, const float* __restrict__ bsV,
    u16* __restrict__ O)
{
    extern __shared__ char smem[];
    const int id = blockIdx.x;
    const int xcd = id & 7, slot = id >> 3;
    const int b = xcd*4 + (slot & 3), h = slot >> 2;
    const int tid = threadIdx.x, wave = tid >> 6, lane = tid & 63;
    const int lr = lane & 15, lg = lane >> 4, lr7 = lr & 7;
    char* Bnc = smem + 65536;
    const float SCL = 0.18033688011112042f;   // 0.125*log2(e)

    // fragment base pointers (u16 units): frag(i, K32-step s) = base + i*8192 + s*512
    const u16* a0  = xp + ((size_t)(b*32 + wave*2)*64 + lg)*128 + lr*8;
    const u16* bq0 = Wp + ((size_t)(h*4      )*64 + lg)*128 + lr*8;
    const u16* bk0 = Wp + ((size_t)(32 + h*4 )*64 + lg)*128 + lr*8;
    const u16* bv0 = Wp + ((size_t)(64 + h*4 )*64 + lg)*128 + lr*8;

    f32x4 acc[2][4];

    auto run_pass = [&](const u16* bb, bool swap) {
        #pragma unroll
        for (int i = 0; i < 2; ++i)
            #pragma unroll
            for (int j = 0; j < 4; ++j) acc[i][j] = f32x4{0.f,0.f,0.f,0.f};
        v8s afA[2], bfA[4], afB[2], bfB[4];
        #pragma unroll
        for (int i = 0; i < 2; ++i) afA[i] = *(const v8s*)(a0 + i*8192);
        #pragma unroll
        for (int j = 0; j < 4; ++j) bfA[j] = *(const v8s*)(bb + j*8192);
        #pragma unroll
        for (int tp = 0; tp < 8; ++tp) {
            #pragma unroll
            for (int i = 0; i < 2; ++i) afB[i] = *(const v8s*)(a0 + (2*tp + 1)*512 + i*8192);
            #pragma unroll
            for (int j = 0; j < 4; ++j) bfB[j] = *(const v8s*)(bb + (2*tp + 1)*512 + j*8192);
            #pragma unroll
            for (int i = 0; i < 2; ++i)
                #pragma unroll
                for (int j = 0; j < 4; ++j)
                    acc[i][j] = swap
                        ? __builtin_amdgcn_mfma_f32_16x16x32_bf16(bfA[j], afA[i], acc[i][j], 0, 0, 0)
                        : __builtin_amdgcn_mfma_f32_16x16x32_bf16(afA[i], bfA[j], acc[i][j], 0, 0, 0);
            if (tp < 7) {
                #pragma unroll
                for (int i = 0; i < 2; ++i) afA[i] = *(const v8s*)(a0 + (2*tp + 2)*512 + i*8192);
                #pragma unroll
                for (int j = 0; j < 4; ++j) bfA[j] = *(const v8s*)(bb + (2*tp + 2)*512 + j*8192);
            }
            #pragma unroll
            for (int i = 0; i < 2; ++i)
                #pragma unroll
                for (int j = 0; j < 4; ++j)
                    acc[i][j] = swap
                        ? __builtin_amdgcn_mfma_f32_16x16x32_bf16(bfB[j], afB[i], acc[i][j], 0, 0, 0)
                        : __builtin_amdgcn_mfma_f32_16x16x32_bf16(afB[i], bfB[j], acc[i][j], 0, 0, 0);
        }
    };

    // ---- q pass: swapped acc; lane: tok = wave*32+i*16+lr, d = j*16+lg*4+{0..3} ----
    run_pass(bq0, true);
    #pragma unroll
    for (int j = 0; j < 4; ++j) {
        float4 b4 = *(const float4*)(bsQ + h*64 + j*16 + lg*4);
        #pragma unroll
        for (int i = 0; i < 2; ++i) {
            int tok = wave*32 + i*16 + lr;
            float v0 = (acc[i][j][0] + b4.x)*SCL, v1 = (acc[i][j][1] + b4.y)*SCL;
            float v2 = (acc[i][j][2] + b4.z)*SCL, v3 = (acc[i][j][3] + b4.w)*SCL;
            int chunk = 2*j + (lg >> 1);
            *(uint2*)(Bnc + tok*128 + ((chunk ^ lr7) << 4) + (lg & 1)*8)
                = make_uint2(cvt_pk_bf16(v0, v1), cvt_pk_bf16(v2, v3));
        }
    }
    v8s qa[2][2];
    #pragma unroll
    for (int ti = 0; ti < 2; ++ti) {
        const char* qr = Bnc + (wave*32 + ti*16 + lr)*128;
        qa[ti][0] = *(const v8s*)(qr + ((lg ^ lr7) << 4));
        qa[ti][1] = *(const v8s*)(qr + (((4 | lg) ^ lr7) << 4));
    }

    // ---- k pass: swapped acc -> K_lds ----
    run_pass(bk0, true);
    #pragma unroll
    for (int j = 0; j < 4; ++j) {
        float4 b4 = *(const float4*)(bsK + h*64 + j*16 + lg*4);
        #pragma unroll
        for (int i = 0; i < 2; ++i) {
            int tok = wave*32 + i*16 + lr;
            float v0 = acc[i][j][0] + b4.x, v1 = acc[i][j][1] + b4.y;
            float v2 = acc[i][j][2] + b4.z, v3 = acc[i][j][3] + b4.w;
            int chunk = 2*j + (lg >> 1);
            *(uint2*)(smem + tok*128 + ((chunk ^ lr7) << 4) + (lg & 1)*8)
                = make_uint2(cvt_pk_bf16(v0, v1), cvt_pk_bf16(v2, v3));
        }
    }
    __syncthreads();   // all qa reads done + K visible

    // ---- v pass: normal acc; lane: d = j*16+lr, toks = wave*32+i*16+lg*4+{0..3} ----
    run_pass(bv0, false);
    #pragma unroll
    for (int j = 0; j < 4; ++j) {
        #pragma unroll
        for (int i = 0; i < 2; ++i) {
            int d = j*16 + lr;
            float bv = bsV[h*64 + d];
            int chunk = wave*4 + 2*i + (lg >> 1);
            *(uint2*)(Bnc + d*1024 + ((chunk ^ lr7) << 4) + (lg & 1)*8)
                = make_uint2(cvt_pk_bf16(acc[i][j][0] + bv, acc[i][j][1] + bv),
                             cvt_pk_bf16(acc[i][j][2] + bv, acc[i][j][3] + bv));
        }
    }
    __syncthreads();   // VT ready

    // ---- attention core: each wave handles 32 queries ----
    const int q0 = wave*32;
    f32x4 o[2][4] = {};
    float ssum[2] = {0.f, 0.f};

    #pragma unroll 1
    for (int c = 0; c < 16; ++c) {
        const char* kr0 = (const char*)smem + ((2*c  )*16 + lr)*128;
        const char* kr1 = (const char*)smem + ((2*c+1)*16 + lr)*128;
        v8s kA0 = *(const v8s*)(kr0 + ((lg ^ lr7) << 4));
        v8s kA1 = *(const v8s*)(kr0 + (((4|lg) ^ lr7) << 4));
        v8s kB0 = *(const v8s*)(kr1 + ((lg ^ lr7) << 4));
        v8s kB1 = *(const v8s*)(kr1 + (((4|lg) ^ lr7) << 4));
        v8s vf[4];
        #pragma unroll
        for (int dt = 0; dt < 4; ++dt) {
            const char* vr = Bnc + (dt*16 + lr)*1024;
            int c0 = c*4 + (lg >> 1), rem = (lg & 1)*8;
            uint2 lo = *(const uint2*)(vr + (((c0    ) ^ lr7) << 4) + rem);
            uint2 hi = *(const uint2*)(vr + (((c0 + 2) ^ lr7) << 4) + rem);
            uint4 u = make_uint4(lo.x, lo.y, hi.x, hi.y);
            vf[dt] = *(v8s*)&u;
        }
        #pragma unroll
        for (int ti = 0; ti < 2; ++ti) {
            __builtin_amdgcn_s_setprio(1);
            f32x4 s0 = {0.f,0.f,0.f,0.f}, s1 = {0.f,0.f,0.f,0.f};
            s0 = __builtin_amdgcn_mfma_f32_16x16x32_bf16(kA0, qa[ti][0], s0, 0, 0, 0);
            s0 = __builtin_amdgcn_mfma_f32_16x16x32_bf16(kA1, qa[ti][1], s0, 0, 0, 0);
            s1 = __builtin_amdgcn_mfma_f32_16x16x32_bf16(kB0, qa[ti][0], s1, 0, 0, 0);
            s1 = __builtin_amdgcn_mfma_f32_16x16x32_bf16(kB1, qa[ti][1], s1, 0, 0, 0);
            __builtin_amdgcn_s_setprio(0);
            float p0 = exp2f(s0[0]), p1 = exp2f(s0[1]), p2 = exp2f(s0[2]), p3 = exp2f(s0[3]);
            float r0 = exp2f(s1[0]), r1 = exp2f(s1[1]), r2 = exp2f(s1[2]), r3 = exp2f(s1[3]);
            ssum[ti] += ((p0 + p1) + (p2 + p3)) + ((r0 + r1) + (r2 + r3));
            unsigned a0w = cvt_pk_bf16(p0, p1), a1w = cvt_pk_bf16(p2, p3);
            unsigned b0w = cvt_pk_bf16(r0, r1), b1w = cvt_pk_bf16(r2, r3);
            uint4 pu = make_uint4(a0w, a1w, b0w, b1w);
            v8s pb = *(v8s*)&pu;
            __builtin_amdgcn_s_setprio(1);
            #pragma unroll
            for (int dt = 0; dt < 4; ++dt)
                o[ti][dt] = __builtin_amdgcn_mfma_f32_16x16x32_bf16(vf[dt], pb, o[ti][dt], 0, 0, 0);
            __builtin_amdgcn_s_setprio(0);
        }
    }

    __syncthreads();   // K/VT dead; LDS reused for O transpose

    float rinv[2];
    #pragma unroll
    for (int ti = 0; ti < 2; ++ti) {
        float v = ssum[ti];
        v += __shfl_xor(v, 16);
        v += __shfl_xor(v, 32);
        rinv[ti] = 1.f / v;
    }

    char* ow = (char*)smem + wave*5120;      // 32 rows x 160B per wave (80KB total)
    #pragma unroll
    for (int ti = 0; ti < 2; ++ti) {
        #pragma unroll
        for (int dt = 0; dt < 4; ++dt) {
            unsigned d0 = cvt_pk_bf16(o[ti][dt][0]*rinv[ti], o[ti][dt][1]*rinv[ti]);
            unsigned d1 = cvt_pk_bf16(o[ti][dt][2]*rinv[ti], o[ti][dt][3]*rinv[ti]);
            *(uint2*)(ow + (ti*16 + lr)*160 + dt*32 + lg*8) = make_uint2(d0, d1);
        }
    }
    __asm__ volatile("s_waitcnt lgkmcnt(0)" ::: "memory");
    #pragma unroll
    for (int it = 0; it < 4; ++it) {
        int rr2 = it*8 + (lane >> 3);
        uint4 v = *(const uint4*)(ow + rr2*160 + (lane & 7)*16);
        *(uint4*)(O + (size_t)(b*NE + q0 + rr2)*DMODEL + h*EMB + (lane & 7)*8) = v;
    }
}

// ---------------- grand fused LN1 + FF1 + relu + FF2 + residual + LN2 (r16, unchanged) ----------------
__global__ __launch_bounds__(512) void ffln_kernel(
    const u16* __restrict__ At, const u16* __restrict__ xb,
    const float* __restrict__ g1, const float* __restrict__ be1,
    const u16* __restrict__ W1T, const float* __restrict__ b1,
    const u16* __restrict__ W2T, const float* __restrict__ b2,
    const float* __restrict__ g2, const float* __restrict__ be2,
    float* __restrict__ out)
{
    extern __shared__ char smem[];
    char* H    = smem;
    char* F1   = smem + 65536;
    char* BSTa = smem + 98304;
    float* Ps = (float*)(smem + 131072);
    float* Pq = Ps + 128;

    const int tid = threadIdx.x, wave = tid >> 6, lane = tid & 63;
    const int lr = lane & 15, lg = lane >> 4, lr7 = lr & 7;
    const int r0 = blockIdx.x * 64;

    #pragma unroll
    for (int it = 0; it < 8; ++it) {
        int r = wave*8 + it;
        uint4 av = *(const uint4*)(At + (size_t)(r0 + r)*512 + lane*8);
        uint4 xv = *(const uint4*)(xb + (size_t)(r0 + r)*512 + lane*8);
        float v0 = bflo(av.x) + bflo(xv.x), v1 = bfhi(av.x) + bfhi(xv.x);
        float v2 = bflo(av.y) + bflo(xv.y), v3 = bfhi(av.y) + bfhi(xv.y);
        float v4 = bflo(av.z) + bflo(xv.z), v5 = bfhi(av.z) + bfhi(xv.z);
        float v6 = bflo(av.w) + bflo(xv.w), v7 = bfhi(av.w) + bfhi(xv.w);
        float s = ((v0+v1)+(v2+v3)) + ((v4+v5)+(v6+v7));
        float q = ((v0*v0+v1*v1)+(v2*v2+v3*v3)) + ((v4*v4+v5*v5)+(v6*v6+v7*v7));
        #pragma unroll
        for (int d = 1; d < 64; d <<= 1) { s += __shfl_xor(s, d); q += __shfl_xor(q, d); }
        float mu = s * (1.f/512.f);
        float rs = rsqrtf(q * (1.f/512.f) - mu*mu + 1e-5f);
        float4 gA = *(const float4*)(g1 + lane*8), gB = *(const float4*)(g1 + lane*8 + 4);
        float4 eA = *(const float4*)(be1 + lane*8), eB = *(const float4*)(be1 + lane*8 + 4);
        float h0 = (v0-mu)*rs*gA.x + eA.x, h1 = (v1-mu)*rs*gA.y + eA.y;
        float h2 = (v2-mu)*rs*gA.z + eA.z, h3 = (v3-mu)*rs*gA.w + eA.w;
        float h4 = (v4-mu)*rs*gB.x + eB.x, h5 = (v5-mu)*rs*gB.y + eB.y;
        float h6 = (v6-mu)*rs*gB.z + eB.z, h7 = (v7-mu)*rs*gB.w + eB.w;
        uint4 hw = make_uint4(cvt_pk_bf16(h0,h1), cvt_pk_bf16(h2,h3),
                              cvt_pk_bf16(h4,h5), cvt_pk_bf16(h6,h7));
        *(uint4*)(H + r*1024 + ((lane ^ (r & 7)) << 4)) = hw;
    }
    __syncthreads();

    const int wr = (wave & 3)*16, wcB = (wave >> 2)*128;

    auto stageW1 = [&](char* buf, int s8) {
        int k0 = s8*64;
        #pragma unroll
        for (int i = 0; i < 4; ++i) {
            int slot = i*512 + tid;
            int row = slot >> 3, ch = slot & 7;
            GLOAD16(W1T + (size_t)row*512 + k0 + ((ch ^ (row & 7)) << 3),
                    buf + i*8192 + wave*1024);
        }
    };
    stageW1(BSTa, 0);
    f32x4 acc1[8] = {};
    #pragma unroll
    for (int s8 = 0; s8 < 8; ++s8) {
        char* cur = (s8 & 1) ? F1 : BSTa;
        asm volatile("s_waitcnt vmcnt(0)" ::: "memory");
        __builtin_amdgcn_s_barrier();
        if (s8 + 1 < 8) stageW1((s8 & 1) ? BSTa : F1, s8 + 1);
        #pragma unroll
        for (int kk = 0; kk < 2; ++kk) {
            v8s af = *(const v8s*)(H + (wr + lr)*1024 + (((s8*8 + kk*4 + lg) ^ lr7) << 4));
            v8s bf[8];
            #pragma unroll
            for (int j = 0; j < 8; ++j)
                bf[j] = *(const v8s*)(cur + (wcB + j*16 + lr)*128 + ((((kk<<2)|lg) ^ lr7) << 4));
            #pragma unroll
            for (int j = 0; j < 8; ++j)
                acc1[j] = __builtin_amdgcn_mfma_f32_16x16x32_bf16(bf[j], af, acc1[j], 0, 0, 0);
        }
    }
    __syncthreads();

    {
        int row = wr + lr;
        #pragma unroll
        for (int j = 0; j < 8; ++j) {
            int col0 = wcB + j*16 + lg*4;
            float4 b4 = *(const float4*)(b1 + col0);
            float v0 = fmaxf(acc1[j][0] + b4.x, 0.f), v1 = fmaxf(acc1[j][1] + b4.y, 0.f);
            float v2 = fmaxf(acc1[j][2] + b4.z, 0.f), v3 = fmaxf(acc1[j][3] + b4.w, 0.f);
            *(uint2*)(F1 + row*512 + (((col0 >> 3) ^ (row & 7)) << 4) + (col0 & 7)*2)
                = make_uint2(cvt_pk_bf16(v0, v1), cvt_pk_bf16(v2, v3));
        }
    }

    const int row = wr + lr;
    uint2 hres[2][8];
    #pragma unroll
    for (int nh = 0; nh < 2; ++nh)
        #pragma unroll
        for (int j = 0; j < 8; ++j) {
            int col0 = nh*256 + wcB + j*16 + lg*4;
            hres[nh][j] = *(const uint2*)(H + row*1024 +
                            ((((col0 & 511) >> 3) ^ (row & 7)) << 4) + (col0 & 7)*2);
        }
    __syncthreads();

    auto stageW2 = [&](char* buf, int g) {
        int nh = g >> 2, k0 = (g & 3)*64;
        #pragma unroll
        for (int i = 0; i < 4; ++i) {
            int slot = i*512 + tid;
            int rw = slot >> 3, ch = slot & 7;
            GLOAD16(W2T + (size_t)(nh*256 + rw)*256 + k0 + ((ch ^ (rw & 7)) << 3),
                    buf + i*8192 + wave*1024);
        }
    };
    stageW2(H, 0);
    f32x4 acc2[2][8] = {};
    #pragma unroll
    for (int g = 0; g < 8; ++g) {
        char* cur = (g & 1) ? (H + 32768) : H;
        asm volatile("s_waitcnt vmcnt(0)" ::: "memory");
        __builtin_amdgcn_s_barrier();
        if (g + 1 < 8) stageW2((g & 1) ? H : (H + 32768), g + 1);
        const int nh = g >> 2, s4 = g & 3;
        #pragma unroll
        for (int kk = 0; kk < 2; ++kk) {
            v8s af = *(const v8s*)(F1 + (wr + lr)*512 + (((s4*8 + kk*4 + lg) ^ lr7) << 4));
            v8s bf[8];
            #pragma unroll
            for (int j = 0; j < 8; ++j)
                bf[j] = *(const v8s*)(cur + (wcB + j*16 + lr)*128 + ((((kk<<2)|lg) ^ lr7) << 4));
            #pragma unroll
            for (int j = 0; j < 8; ++j)
                acc2[nh][j] = __builtin_amdgcn_mfma_f32_16x16x32_bf16(bf[j], af, acc2[nh][j], 0, 0, 0);
        }
    }

    float s = 0.f, q = 0.f;
    #pragma unroll
    for (int nh = 0; nh < 2; ++nh) {
        #pragma unroll
        for (int j = 0; j < 8; ++j) {
            int col0 = nh*256 + wcB + j*16 + lg*4;
            float4 b4 = *(const float4*)(b2 + col0);
            uint2 hh = hres[nh][j];
            f32x4 a = acc2[nh][j];
            a[0] += b4.x + bflo(hh.x); a[1] += b4.y + bfhi(hh.x);
            a[2] += b4.z + bflo(hh.y); a[3] += b4.w + bfhi(hh.y);
            acc2[nh][j] = a;
            s += (a[0]+a[1]) + (a[2]+a[3]);
            q += (a[0]*a[0]+a[1]*a[1]) + (a[2]*a[2]+a[3]*a[3]);
        }
    }
    s += __shfl_xor(s, 16); s += __shfl_xor(s, 32);
    q += __shfl_xor(q, 16); q += __shfl_xor(q, 32);
    __syncthreads();
    if (lg == 0) { Ps[row*2 + (wave >> 2)] = s; Pq[row*2 + (wave >> 2)] = q; }
    __syncthreads();
    float st = Ps[row*2] + Ps[row*2 + 1];
    float qt = Pq[row*2] + Pq[row*2 + 1];
    float mu = st * (1.f/512.f);
    float rs = rsqrtf(qt * (1.f/512.f) - mu*mu + 1e-5f);

    #pragma unroll
    for (int nh = 0; nh < 2; ++nh) {
        #pragma unroll
        for (int j = 0; j < 8; ++j) {
            int col0 = nh*256 + wcB + j*16 + lg*4;
            float4 gg = *(const float4*)(g2 + col0);
            float4 ee = *(const float4*)(be2 + col0);
            f32x4 a = acc2[nh][j];
            float4 o;
            o.x = (a[0]-mu)*rs*gg.x + ee.x;
            o.y = (a[1]-mu)*rs*gg.y + ee.y;
            o.z = (a[2]-mu)*rs*gg.z + ee.z;
            o.w = (a[3]-mu)*rs*gg.w + ee.w;
            *(float4*)(out + (size_t)(r0 + row)*512 + col0) = o;
        }
    }
}

// ---------------- launcher ----------------

extern "C" void kernel_launch(void* const* d_in, const int* in_sizes, int n_in,
                              void* d_out, int out_size, void* d_ws, size_t ws_size,
                              hipStream_t stream)
{
    const float* x   = (const float*)d_in[0];
    const float* Wq  = (const float*)d_in[1];
    const float* bq  = (const float*)d_in[2];
    const float* Wk  = (const float*)d_in[3];
    const float* bk  = (const float*)d_in[4];
    const float* Wv  = (const float*)d_in[5];
    const float* bv  = (const float*)d_in[6];
    const float* W1  = (const float*)d_in[7];
    const float* bf1 = (const float*)d_in[8];
    const float* W2  = (const float*)d_in[9];
    const float* bf2 = (const float*)d_in[10];
    const float* g1  = (const float*)d_in[11];
    const float* be1 = (const float*)d_in[12];
    const float* g2  = (const float*)d_in[13];
    const float* be2 = (const float*)d_in[14];

    char* ws = (char*)d_ws;
    const size_t MB = 1ull << 20;
    const size_t KB = 1024;
    u16* xb    = (u16*)(ws + 0);          // x bf16 linear — live through ffln
    u16* xp    = (u16*)(ws + 16*MB);      // x packed fragments
    u16* attnb = (u16*)(ws + 32*MB);      // attention output
    u16* Wp    = (u16*)(ws + 48*MB);                 // Wqkv packed [96][64][16][8]
    u16* W1T   = (u16*)(ws + 48*MB + 1536*KB);       // [256][512]
    u16* W2T   = (u16*)(ws + 48*MB + 1792*KB);       // [512][256]
    (void)ws_size; (void)in_sizes; (void)n_in; (void)out_size;

    cvt_all_kernel<<<11520, 256, 0, stream>>>(x, xb, xp, Wq, Wk, Wv, W1, W2, Wp, W1T, W2T);

    fused_attn_kernel<<<256, 1024, 131072, stream>>>(xp, Wp, bq, bk, bv, attnb);

    ffln_kernel<<<256, 512, 132096, stream>>>(attnb, xb, g1, be1, W1T, bf1, W2T, bf2,
                                              g2, be2, (float*)d_out);
}

// Round 20
// 96.978 us; speedup vs baseline: 1.4163x; 1.1597x over previous
//
#include <hip/hip_runtime.h>

#define BS 32
#define NE 512
#define DMODEL 512
#define HEADS 8
#define EMB 64
#define FFH 256
#define MTOK (BS*NE)   // 16384

typedef unsigned short u16;
typedef short v8s __attribute__((ext_vector_type(8)));
typedef float f32x4 __attribute__((ext_vector_type(4)));
typedef u16 u16x4 __attribute__((ext_vector_type(4)));

#define GLOAD16(G, L) \
  __builtin_amdgcn_global_load_lds((const __attribute__((address_space(1))) unsigned int*)(G), \
      (__attribute__((address_space(3))) unsigned int*)(L), 16, 0, 0)

static __device__ __forceinline__ unsigned cvt_pk_bf16(float lo, float hi) {
    unsigned r;
    asm("v_cvt_pk_bf16_f32 %0, %1, %2" : "=v"(r) : "v"(lo), "v"(hi));
    return r;
}

static __device__ __forceinline__ u16 f2bf_bits(float f) {
    unsigned u = __float_as_uint(f);
    u += 0x7fffu + ((u >> 16) & 1u);   // round-to-nearest-even
    return (u16)(u >> 16);
}
static __device__ __forceinline__ float bflo(unsigned w) { return __uint_as_float(w << 16); }
static __device__ __forceinline__ float bfhi(unsigned w) { return __uint_as_float(w & 0xffff0000u); }

// ---------------- fused conversion (r18, unchanged) ----------------
__global__ __launch_bounds__(256) void cvt_all_kernel(
    const float* __restrict__ x, u16* __restrict__ xb, u16* __restrict__ xp,
    const float* __restrict__ Wq, const float* __restrict__ Wk, const float* __restrict__ Wv,
    const float* __restrict__ W1, const float* __restrict__ W2,
    u16* __restrict__ Wp, u16* __restrict__ W1T, u16* __restrict__ W2T)
{
    const int id = blockIdx.x;
    const int tt = threadIdx.x;
    if (id < 8192) {
        int i = id*256 + tt;
        float4 v = ((const float4*)x)[i];
        u16x4 o = { f2bf_bits(v.x), f2bf_bits(v.y), f2bf_bits(v.z), f2bf_bits(v.w) };
        ((u16x4*)xb)[i] = o;
        int e = i * 4;
        int row = e >> 9, k = e & 511;
        *(u16x4*)(xp + ((size_t)(row >> 4)*64 + (k >> 3))*128 + (row & 15)*8 + (k & 7)) = o;
        return;
    }
    if (id < 11264) {                  // Wqkv -> packed
        int widx = (id - 8192)*256 + tt;   // 0..786431
        int w = widx >> 18, rem = widx & 262143;
        int k = rem >> 9, n = rem & 511;
        const float* src = (w == 0) ? Wq : (w == 1) ? Wk : Wv;
        int np = w*512 + n;
        Wp[((size_t)(np >> 4)*64 + (k >> 3))*128 + (np & 15)*8 + (k & 7)] = f2bf_bits(src[rem]);
        return;
    }
    __shared__ float T[32][33];
    const int t2 = id - 11264;         // 0..255
    const float* src; u16* dst; int ldsrc, lddst, sr, sc;
    if (t2 < 128) {                    // W1: 512x256, 16x8 tiles
        int tr = t2 >> 3, tc = t2 & 7;
        src = W1; ldsrc = 256; sr = tr*32; sc = tc*32;
        dst = W1T + (size_t)sc*512 + sr; lddst = 512;
    } else {                           // W2: 256x512, 8x16 tiles
        int t = t2 - 128;
        int tr = t >> 4, tc = t & 15;
        src = W2; ldsrc = 512; sr = tr*32; sc = tc*32;
        dst = W2T + (size_t)sc*256 + sr; lddst = 256;
    }
    {
        int r = tt >> 3, c4 = (tt & 7) << 2;
        float4 v = *(const float4*)(src + (size_t)(sr + r)*ldsrc + sc + c4);
        T[r][c4] = v.x; T[r][c4+1] = v.y; T[r][c4+2] = v.z; T[r][c4+3] = v.w;
    }
    __syncthreads();
    {
        int n = tt >> 3, k4 = (tt & 7) << 2;
        u16x4 o = { f2bf_bits(T[k4][n]), f2bf_bits(T[k4+1][n]),
                    f2bf_bits(T[k4+2][n]), f2bf_bits(T[k4+3][n]) };
        *(u16x4*)(dst + (size_t)n*lddst + k4) = o;
    }
}

// ---------------- fused QKV + attention: 1 block = 1 (b,h), 1024 thr / 16 waves ----------------
// B (weights) staged ONCE per pass into LDS (64KB linear copy) — kills the 16x per-wave
// B re-read that made r19 L2-bandwidth-bound. A streams from packed global (L2).
// Region plan: Wq->R0 | q-epi->R1, qa | Wk->R0 | K->R0 | Wv->R1 | VT->R1 | attn core.
__global__ __launch_bounds__(1024) void fused_attn_kernel(
    const u16* __restrict__ xp, const u16* __restrict__ Wp,
    const float* __restrict__ bsQ, const float* __restrict__ bsK, const float* __restrict__ bsV,
    u16* __restrict__ O)
{
    extern __shared__ char smem[];
    const int id = blockIdx.x;
    const int xcd = id & 7, slot = id >> 3;
    const int b = xcd*4 + (slot & 3), h = slot >> 2;
    const int tid = threadIdx.x, wave = tid >> 6, lane = tid & 63;
    const int lr = lane & 15, lg = lane >> 4, lr7 = lr & 7;
    char* R0 = smem;                 // 64KB: Wq / Wk staging, then K_lds
    char* R1 = smem + 65536;         // 64KB: q-bounce, then Wv staging, then VT
    const float SCL = 0.18033688011112042f;   // 0.125*log2(e)

    // A fragment base (u16): frag(i, K32-step s) = a0 + i*8192 + s*512
    const u16* a0 = xp + ((size_t)(b*32 + wave*2)*64 + lg)*128 + lr*8;
    // W region bases (u16), each 32768 u16 = 64KB contiguous in packed layout
    const u16* Wqb = Wp + (size_t)h*32768;
    const u16* Wkb = Wp + 262144 + (size_t)h*32768;
    const u16* Wvb = Wp + 524288 + (size_t)h*32768;

    auto stageB = [&](const u16* Wb, char* R) {
        #pragma unroll
        for (int r = 0; r < 4; ++r)
            GLOAD16(Wb + r*8192 + wave*512 + lane*8, R + r*16384 + wave*1024);
    };

    f32x4 acc[2][4];

    // B fragment (bytes in region): j*16384 + s*1024 + lg*256 + lr*16
    auto run_pass = [&](const char* Rb, bool swap) {
        #pragma unroll
        for (int i = 0; i < 2; ++i)
            #pragma unroll
            for (int j = 0; j < 4; ++j) acc[i][j] = f32x4{0.f,0.f,0.f,0.f};
        v8s afA[2], bfA[4], afB[2], bfB[4];
        const char* rb = Rb + lg*256 + lr*16;
        #pragma unroll
        for (int i = 0; i < 2; ++i) afA[i] = *(const v8s*)(a0 + i*8192);
        #pragma unroll
        for (int j = 0; j < 4; ++j) bfA[j] = *(const v8s*)(rb + j*16384);
        #pragma unroll
        for (int tp = 0; tp < 8; ++tp) {
            #pragma unroll
            for (int i = 0; i < 2; ++i) afB[i] = *(const v8s*)(a0 + (2*tp + 1)*512 + i*8192);
            #pragma unroll
            for (int j = 0; j < 4; ++j) bfB[j] = *(const v8s*)(rb + (2*tp + 1)*1024 + j*16384);
            #pragma unroll
            for (int i = 0; i < 2; ++i)
                #pragma unroll
                for (int j = 0; j < 4; ++j)
                    acc[i][j] = swap
                        ? __builtin_amdgcn_mfma_f32_16x16x32_bf16(bfA[j], afA[i], acc[i][j], 0, 0, 0)
                        : __builtin_amdgcn_mfma_f32_16x16x32_bf16(afA[i], bfA[j], acc[i][j], 0, 0, 0);
            if (tp < 7) {
                #pragma unroll
                for (int i = 0; i < 2; ++i) afA[i] = *(const v8s*)(a0 + (2*tp + 2)*512 + i*8192);
                #pragma unroll
                for (int j = 0; j < 4; ++j) bfA[j] = *(const v8s*)(rb + (2*tp + 2)*1024 + j*16384);
            }
            #pragma unroll
            for (int i = 0; i < 2; ++i)
                #pragma unroll
                for (int j = 0; j < 4; ++j)
                    acc[i][j] = swap
                        ? __builtin_amdgcn_mfma_f32_16x16x32_bf16(bfB[j], afB[i], acc[i][j], 0, 0, 0)
                        : __builtin_amdgcn_mfma_f32_16x16x32_bf16(afB[i], bfB[j], acc[i][j], 0, 0, 0);
        }
    };

    // ---- q pass ----
    stageB(Wqb, R0);
    __syncthreads();
    run_pass(R0, true);
    #pragma unroll
    for (int j = 0; j < 4; ++j) {
        float4 b4 = *(const float4*)(bsQ + h*64 + j*16 + lg*4);
        #pragma unroll
        for (int i = 0; i < 2; ++i) {
            int tok = wave*32 + i*16 + lr;
            float v0 = (acc[i][j][0] + b4.x)*SCL, v1 = (acc[i][j][1] + b4.y)*SCL;
            float v2 = (acc[i][j][2] + b4.z)*SCL, v3 = (acc[i][j][3] + b4.w)*SCL;
            int chunk = 2*j + (lg >> 1);
            *(uint2*)(R1 + tok*128 + ((chunk ^ lr7) << 4) + (lg & 1)*8)
                = make_uint2(cvt_pk_bf16(v0, v1), cvt_pk_bf16(v2, v3));
        }
    }
    v8s qa[2][2];
    #pragma unroll
    for (int ti = 0; ti < 2; ++ti) {
        const char* qr = R1 + (wave*32 + ti*16 + lr)*128;
        qa[ti][0] = *(const v8s*)(qr + ((lg ^ lr7) << 4));
        qa[ti][1] = *(const v8s*)(qr + (((4 | lg) ^ lr7) << 4));
    }
    __syncthreads();   // Wq reads + bounce reads done

    // ---- k pass ----
    stageB(Wkb, R0);
    __syncthreads();
    run_pass(R0, true);
    __syncthreads();   // all Wk reads done before K overwrites R0
    #pragma unroll
    for (int j = 0; j < 4; ++j) {
        float4 b4 = *(const float4*)(bsK + h*64 + j*16 + lg*4);
        #pragma unroll
        for (int i = 0; i < 2; ++i) {
            int tok = wave*32 + i*16 + lr;
            float v0 = acc[i][j][0] + b4.x, v1 = acc[i][j][1] + b4.y;
            float v2 = acc[i][j][2] + b4.z, v3 = acc[i][j][3] + b4.w;
            int chunk = 2*j + (lg >> 1);
            *(uint2*)(R0 + tok*128 + ((chunk ^ lr7) << 4) + (lg & 1)*8)
                = make_uint2(cvt_pk_bf16(v0, v1), cvt_pk_bf16(v2, v3));
        }
    }
    stageB(Wvb, R1);   // overlaps with K epilogue writes (disjoint regions)
    __syncthreads();   // K visible + Wv loaded

    // ---- v pass ----
    run_pass(R1, false);
    __syncthreads();   // all Wv reads done before VT overwrites R1
    #pragma unroll
    for (int j = 0; j < 4; ++j) {
        #pragma unroll
        for (int i = 0; i < 2; ++i) {
            int d = j*16 + lr;
            float bv = bsV[h*64 + d];
            int chunk = wave*4 + 2*i + (lg >> 1);
            *(uint2*)(R1 + d*1024 + ((chunk ^ lr7) << 4) + (lg & 1)*8)
                = make_uint2(cvt_pk_bf16(acc[i][j][0] + bv, acc[i][j][1] + bv),
                             cvt_pk_bf16(acc[i][j][2] + bv, acc[i][j][3] + bv));
        }
    }
    __syncthreads();   // VT ready

    // ---- attention core: each wave handles 32 queries ----
    const int q0 = wave*32;
    f32x4 o[2][4] = {};
    float ssum[2] = {0.f, 0.f};

    #pragma unroll 1
    for (int c = 0; c < 16; ++c) {
        const char* kr0 = R0 + ((2*c  )*16 + lr)*128;
        const char* kr1 = R0 + ((2*c+1)*16 + lr)*128;
        v8s kA0 = *(const v8s*)(kr0 + ((lg ^ lr7) << 4));
        v8s kA1 = *(const v8s*)(kr0 + (((4|lg) ^ lr7) << 4));
        v8s kB0 = *(const v8s*)(kr1 + ((lg ^ lr7) << 4));
        v8s kB1 = *(const v8s*)(kr1 + (((4|lg) ^ lr7) << 4));
        v8s vf[4];
        #pragma unroll
        for (int dt = 0; dt < 4; ++dt) {
            const char* vr = R1 + (dt*16 + lr)*1024;
            int c0 = c*4 + (lg >> 1), rem = (lg & 1)*8;
            uint2 lo = *(const uint2*)(vr + (((c0    ) ^ lr7) << 4) + rem);
            uint2 hi = *(const uint2*)(vr + (((c0 + 2) ^ lr7) << 4) + rem);
            uint4 u = make_uint4(lo.x, lo.y, hi.x, hi.y);
            vf[dt] = *(v8s*)&u;
        }
        #pragma unroll
        for (int ti = 0; ti < 2; ++ti) {
            __builtin_amdgcn_s_setprio(1);
            f32x4 s0 = {0.f,0.f,0.f,0.f}, s1 = {0.f,0.f,0.f,0.f};
            s0 = __builtin_amdgcn_mfma_f32_16x16x32_bf16(kA0, qa[ti][0], s0, 0, 0, 0);
            s0 = __builtin_amdgcn_mfma_f32_16x16x32_bf16(kA1, qa[ti][1], s0, 0, 0, 0);
            s1 = __builtin_amdgcn_mfma_f32_16x16x32_bf16(kB0, qa[ti][0], s1, 0, 0, 0);
            s1 = __builtin_amdgcn_mfma_f32_16x16x32_bf16(kB1, qa[ti][1], s1, 0, 0, 0);
            __builtin_amdgcn_s_setprio(0);
            float p0 = exp2f(s0[0]), p1 = exp2f(s0[1]), p2 = exp2f(s0[2]), p3 = exp2f(s0[3]);
            float r0 = exp2f(s1[0]), r1 = exp2f(s1[1]), r2 = exp2f(s1[2]), r3 = exp2f(s1[3]);
            ssum[ti] += ((p0 + p1) + (p2 + p3)) + ((r0 + r1) + (r2 + r3));
            unsigned a0w = cvt_pk_bf16(p0, p1), a1w = cvt_pk_bf16(p2, p3);
            unsigned b0w = cvt_pk_bf16(r0, r1), b1w = cvt_pk_bf16(r2, r3);
            uint4 pu = make_uint4(a0w, a1w, b0w, b1w);
            v8s pb = *(v8s*)&pu;
            __builtin_amdgcn_s_setprio(1);
            #pragma unroll
            for (int dt = 0; dt < 4; ++dt)
                o[ti][dt] = __builtin_amdgcn_mfma_f32_16x16x32_bf16(vf[dt], pb, o[ti][dt], 0, 0, 0);
            __builtin_amdgcn_s_setprio(0);
        }
    }

    __syncthreads();   // K/VT dead; LDS reused for O transpose

    float rinv[2];
    #pragma unroll
    for (int ti = 0; ti < 2; ++ti) {
        float v = ssum[ti];
        v += __shfl_xor(v, 16);
        v += __shfl_xor(v, 32);
        rinv[ti] = 1.f / v;
    }

    char* ow = (char*)smem + wave*5120;      // 32 rows x 160B per wave (80KB total)
    #pragma unroll
    for (int ti = 0; ti < 2; ++ti) {
        #pragma unroll
        for (int dt = 0; dt < 4; ++dt) {
            unsigned d0 = cvt_pk_bf16(o[ti][dt][0]*rinv[ti], o[ti][dt][1]*rinv[ti]);
            unsigned d1 = cvt_pk_bf16(o[ti][dt][2]*rinv[ti], o[ti][dt][3]*rinv[ti]);
            *(uint2*)(ow + (ti*16 + lr)*160 + dt*32 + lg*8) = make_uint2(d0, d1);
        }
    }
    __asm__ volatile("s_waitcnt lgkmcnt(0)" ::: "memory");
    #pragma unroll
    for (int it = 0; it < 4; ++it) {
        int rr2 = it*8 + (lane >> 3);
        uint4 v = *(const uint4*)(ow + rr2*160 + (lane & 7)*16);
        *(uint4*)(O + (size_t)(b*NE + q0 + rr2)*DMODEL + h*EMB + (lane & 7)*8) = v;
    }
}

// ---------------- grand fused LN1 + FF1 + relu + FF2 + residual + LN2 (r16, unchanged) ----------------
__global__ __launch_bounds__(512) void ffln_kernel(
    const u16* __restrict__ At, const u16* __restrict__ xb,
    const float* __restrict__ g1, const float* __restrict__ be1,
    const u16* __restrict__ W1T, const float* __restrict__ b1,
    const u16* __restrict__ W2T, const float* __restrict__ b2,
    const float* __restrict__ g2, const float* __restrict__ be2,
    float* __restrict__ out)
{
    extern __shared__ char smem[];
    char* H    = smem;
    char* F1   = smem + 65536;
    char* BSTa = smem + 98304;
    float* Ps = (float*)(smem + 131072);
    float* Pq = Ps + 128;

    const int tid = threadIdx.x, wave = tid >> 6, lane = tid & 63;
    const int lr = lane & 15, lg = lane >> 4, lr7 = lr & 7;
    const int r0 = blockIdx.x * 64;

    #pragma unroll
    for (int it = 0; it < 8; ++it) {
        int r = wave*8 + it;
        uint4 av = *(const uint4*)(At + (size_t)(r0 + r)*512 + lane*8);
        uint4 xv = *(const uint4*)(xb + (size_t)(r0 + r)*512 + lane*8);
        float v0 = bflo(av.x) + bflo(xv.x), v1 = bfhi(av.x) + bfhi(xv.x);
        float v2 = bflo(av.y) + bflo(xv.y), v3 = bfhi(av.y) + bfhi(xv.y);
        float v4 = bflo(av.z) + bflo(xv.z), v5 = bfhi(av.z) + bfhi(xv.z);
        float v6 = bflo(av.w) + bflo(xv.w), v7 = bfhi(av.w) + bfhi(xv.w);
        float s = ((v0+v1)+(v2+v3)) + ((v4+v5)+(v6+v7));
        float q = ((v0*v0+v1*v1)+(v2*v2+v3*v3)) + ((v4*v4+v5*v5)+(v6*v6+v7*v7));
        #pragma unroll
        for (int d = 1; d < 64; d <<= 1) { s += __shfl_xor(s, d); q += __shfl_xor(q, d); }
        float mu = s * (1.f/512.f);
        float rs = rsqrtf(q * (1.f/512.f) - mu*mu + 1e-5f);
        float4 gA = *(const float4*)(g1 + lane*8), gB = *(const float4*)(g1 + lane*8 + 4);
        float4 eA = *(const float4*)(be1 + lane*8), eB = *(const float4*)(be1 + lane*8 + 4);
        float h0 = (v0-mu)*rs*gA.x + eA.x, h1 = (v1-mu)*rs*gA.y + eA.y;
        float h2 = (v2-mu)*rs*gA.z + eA.z, h3 = (v3-mu)*rs*gA.w + eA.w;
        float h4 = (v4-mu)*rs*gB.x + eB.x, h5 = (v5-mu)*rs*gB.y + eB.y;
        float h6 = (v6-mu)*rs*gB.z + eB.z, h7 = (v7-mu)*rs*gB.w + eB.w;
        uint4 hw = make_uint4(cvt_pk_bf16(h0,h1), cvt_pk_bf16(h2,h3),
                              cvt_pk_bf16(h4,h5), cvt_pk_bf16(h6,h7));
        *(uint4*)(H + r*1024 + ((lane ^ (r & 7)) << 4)) = hw;
    }
    __syncthreads();

    const int wr = (wave & 3)*16, wcB = (wave >> 2)*128;

    auto stageW1 = [&](char* buf, int s8) {
        int k0 = s8*64;
        #pragma unroll
        for (int i = 0; i < 4; ++i) {
            int slot = i*512 + tid;
            int row = slot >> 3, ch = slot & 7;
            GLOAD16(W1T + (size_t)row*512 + k0 + ((ch ^ (row & 7)) << 3),
                    buf + i*8192 + wave*1024);
        }
    };
    stageW1(BSTa, 0);
    f32x4 acc1[8] = {};
    #pragma unroll
    for (int s8 = 0; s8 < 8; ++s8) {
        char* cur = (s8 & 1) ? F1 : BSTa;
        asm volatile("s_waitcnt vmcnt(0)" ::: "memory");
        __builtin_amdgcn_s_barrier();
        if (s8 + 1 < 8) stageW1((s8 & 1) ? BSTa : F1, s8 + 1);
        #pragma unroll
        for (int kk = 0; kk < 2; ++kk) {
            v8s af = *(const v8s*)(H + (wr + lr)*1024 + (((s8*8 + kk*4 + lg) ^ lr7) << 4));
            v8s bf[8];
            #pragma unroll
            for (int j = 0; j < 8; ++j)
                bf[j] = *(const v8s*)(cur + (wcB + j*16 + lr)*128 + ((((kk<<2)|lg) ^ lr7) << 4));
            #pragma unroll
            for (int j = 0; j < 8; ++j)
                acc1[j] = __builtin_amdgcn_mfma_f32_16x16x32_bf16(bf[j], af, acc1[j], 0, 0, 0);
        }
    }
    __syncthreads();

    {
        int row = wr + lr;
        #pragma unroll
        for (int j = 0; j < 8; ++j) {
            int col0 = wcB + j*16 + lg*4;
            float4 b4 = *(const float4*)(b1 + col0);
            float v0 = fmaxf(acc1[j][0] + b4.x, 0.f), v1 = fmaxf(acc1[j][1] + b4.y, 0.f);
            float v2 = fmaxf(acc1[j][2] + b4.z, 0.f), v3 = fmaxf(acc1[j][3] + b4.w, 0.f);
            *(uint2*)(F1 + row*512 + (((col0 >> 3) ^ (row & 7)) << 4) + (col0 & 7)*2)
                = make_uint2(cvt_pk_bf16(v0, v1), cvt_pk_bf16(v2, v3));
        }
    }

    const int row = wr + lr;
    uint2 hres[2][8];
    #pragma unroll
    for (int nh = 0; nh < 2; ++nh)
        #pragma unroll
        for (int j = 0; j < 8; ++j) {
            int col0 = nh*256 + wcB + j*16 + lg*4;
            hres[nh][j] = *(const uint2*)(H + row*1024 +
                            ((((col0 & 511) >> 3) ^ (row & 7)) << 4) + (col0 & 7)*2);
        }
    __syncthreads();

    auto stageW2 = [&](char* buf, int g) {
        int nh = g >> 2, k0 = (g & 3)*64;
        #pragma unroll
        for (int i = 0; i < 4; ++i) {
            int slot = i*512 + tid;
            int rw = slot >> 3, ch = slot & 7;
            GLOAD16(W2T + (size_t)(nh*256 + rw)*256 + k0 + ((ch ^ (rw & 7)) << 3),
                    buf + i*8192 + wave*1024);
        }
    };
    stageW2(H, 0);
    f32x4 acc2[2][8] = {};
    #pragma unroll
    for (int g = 0; g < 8; ++g) {
        char* cur = (g & 1) ? (H + 32768) : H;
        asm volatile("s_waitcnt vmcnt(0)" ::: "memory");
        __builtin_amdgcn_s_barrier();
        if (g + 1 < 8) stageW2((g & 1) ? H : (H + 32768), g + 1);
        const int nh = g >> 2, s4 = g & 3;
        #pragma unroll
        for (int kk = 0; kk < 2; ++kk) {
            v8s af = *(const v8s*)(F1 + (wr + lr)*512 + (((s4*8 + kk*4 + lg) ^ lr7) << 4));
            v8s bf[8];
            #pragma unroll
            for (int j = 0; j < 8; ++j)
                bf[j] = *(const v8s*)(cur + (wcB + j*16 + lr)*128 + ((((kk<<2)|lg) ^ lr7) << 4));
            #pragma unroll
            for (int j = 0; j < 8; ++j)
                acc2[nh][j] = __builtin_amdgcn_mfma_f32_16x16x32_bf16(bf[j], af, acc2[nh][j], 0, 0, 0);
        }
    }

    float s = 0.f, q = 0.f;
    #pragma unroll
    for (int nh = 0; nh < 2; ++nh) {
        #pragma unroll
        for (int j = 0; j < 8; ++j) {
            int col0 = nh*256 + wcB + j*16 + lg*4;
            float4 b4 = *(const float4*)(b2 + col0);
            uint2 hh = hres[nh][j];
            f32x4 a = acc2[nh][j];
            a[0] += b4.x + bflo(hh.x); a[1] += b4.y + bfhi(hh.x);
            a[2] += b4.z + bflo(hh.y); a[3] += b4.w + bfhi(hh.y);
            acc2[nh][j] = a;
            s += (a[0]+a[1]) + (a[2]+a[3]);
            q += (a[0]*a[0]+a[1]*a[1]) + (a[2]*a[2]+a[3]*a[3]);
        }
    }
    s += __shfl_xor(s, 16); s += __shfl_xor(s, 32);
    q += __shfl_xor(q, 16); q += __shfl_xor(q, 32);
    __syncthreads();
    if (lg == 0) { Ps[row*2 + (wave >> 2)] = s; Pq[row*2 + (wave >> 2)] = q; }
    __syncthreads();
    float st = Ps[row*2] + Ps[row*2 + 1];
    float qt = Pq[row*2] + Pq[row*2 + 1];
    float mu = st * (1.f/512.f);
    float rs = rsqrtf(qt * (1.f/512.f) - mu*mu + 1e-5f);

    #pragma unroll
    for (int nh = 0; nh < 2; ++nh) {
        #pragma unroll
        for (int j = 0; j < 8; ++j) {
            int col0 = nh*256 + wcB + j*16 + lg*4;
            float4 gg = *(const float4*)(g2 + col0);
            float4 ee = *(const float4*)(be2 + col0);
            f32x4 a = acc2[nh][j];
            float4 o;
            o.x = (a[0]-mu)*rs*gg.x + ee.x;
            o.y = (a[1]-mu)*rs*gg.y + ee.y;
            o.z = (a[2]-mu)*rs*gg.z + ee.z;
            o.w = (a[3]-mu)*rs*gg.w + ee.w;
            *(float4*)(out + (size_t)(r0 + row)*512 + col0) = o;
        }
    }
}

// ---------------- launcher ----------------

extern "C" void kernel_launch(void* const* d_in, const int* in_sizes, int n_in,
                              void* d_out, int out_size, void* d_ws, size_t ws_size,
                              hipStream_t stream)
{
    const float* x   = (const float*)d_in[0];
    const float* Wq  = (const float*)d_in[1];
    const float* bq  = (const float*)d_in[2];
    const float* Wk  = (const float*)d_in[3];
    const float* bk  = (const float*)d_in[4];
    const float* Wv  = (const float*)d_in[5];
    const float* bv  = (const float*)d_in[6];
    const float* W1  = (const float*)d_in[7];
    const float* bf1 = (const float*)d_in[8];
    const float* W2  = (const float*)d_in[9];
    const float* bf2 = (const float*)d_in[10];
    const float* g1  = (const float*)d_in[11];
    const float* be1 = (const float*)d_in[12];
    const float* g2  = (const float*)d_in[13];
    const float* be2 = (const float*)d_in[14];

    char* ws = (char*)d_ws;
    const size_t MB = 1ull << 20;
    const size_t KB = 1024;
    u16* xb    = (u16*)(ws + 0);          // x bf16 linear — live through ffln
    u16* xp    = (u16*)(ws + 16*MB);      // x packed fragments
    u16* attnb = (u16*)(ws + 32*MB);      // attention output
    u16* Wp    = (u16*)(ws + 48*MB);                 // Wqkv packed [96][64][16][8]
    u16* W1T   = (u16*)(ws + 48*MB + 1536*KB);       // [256][512]
    u16* W2T   = (u16*)(ws + 48*MB + 1792*KB);       // [512][256]
    (void)ws_size; (void)in_sizes; (void)n_in; (void)out_size;

    cvt_all_kernel<<<11520, 256, 0, stream>>>(x, xb, xp, Wq, Wk, Wv, W1, W2, Wp, W1T, W2T);

    fused_attn_kernel<<<256, 1024, 131072, stream>>>(xp, Wp, bq, bk, bv, attnb);

    ffln_kernel<<<256, 512, 132096, stream>>>(attnb, xb, g1, be1, W1T, bf1, W2T, bf2,
                                              g2, be2, (float*)d_out);
}

// Round 21
// 96.584 us; speedup vs baseline: 1.4221x; 1.0041x over previous
//
#include <hip/hip_runtime.h>

#define BS 32
#define NE 512
#define DMODEL 512
#define HEADS 8
#define EMB 64
#define FFH 256
#define MTOK (BS*NE)   // 16384

typedef unsigned short u16;
typedef short v8s __attribute__((ext_vector_type(8)));
typedef float f32x4 __attribute__((ext_vector_type(4)));
typedef u16 u16x4 __attribute__((ext_vector_type(4)));

#define GLOAD16(G, L) \
  __builtin_amdgcn_global_load_lds((const __attribute__((address_space(1))) unsigned int*)(G), \
      (__attribute__((address_space(3))) unsigned int*)(L), 16, 0, 0)

static __device__ __forceinline__ unsigned cvt_pk_bf16(float lo, float hi) {
    unsigned r;
    asm("v_cvt_pk_bf16_f32 %0, %1, %2" : "=v"(r) : "v"(lo), "v"(hi));
    return r;
}

static __device__ __forceinline__ u16 f2bf_bits(float f) {
    unsigned u = __float_as_uint(f);
    u += 0x7fffu + ((u >> 16) & 1u);   // round-to-nearest-even
    return (u16)(u >> 16);
}
static __device__ __forceinline__ float bflo(unsigned w) { return __uint_as_float(w << 16); }
static __device__ __forceinline__ float bfhi(unsigned w) { return __uint_as_float(w & 0xffff0000u); }

// ---------------- fused conversion (r18, unchanged) ----------------
__global__ __launch_bounds__(256) void cvt_all_kernel(
    const float* __restrict__ x, u16* __restrict__ xb, u16* __restrict__ xp,
    const float* __restrict__ Wq, const float* __restrict__ Wk, const float* __restrict__ Wv,
    const float* __restrict__ W1, const float* __restrict__ W2,
    u16* __restrict__ Wp, u16* __restrict__ W1T, u16* __restrict__ W2T)
{
    const int id = blockIdx.x;
    const int tt = threadIdx.x;
    if (id < 8192) {
        int i = id*256 + tt;
        float4 v = ((const float4*)x)[i];
        u16x4 o = { f2bf_bits(v.x), f2bf_bits(v.y), f2bf_bits(v.z), f2bf_bits(v.w) };
        ((u16x4*)xb)[i] = o;
        int e = i * 4;
        int row = e >> 9, k = e & 511;
        *(u16x4*)(xp + ((size_t)(row >> 4)*64 + (k >> 3))*128 + (row & 15)*8 + (k & 7)) = o;
        return;
    }
    if (id < 11264) {                  // Wqkv -> packed
        int widx = (id - 8192)*256 + tt;   // 0..786431
        int w = widx >> 18, rem = widx & 262143;
        int k = rem >> 9, n = rem & 511;
        const float* src = (w == 0) ? Wq : (w == 1) ? Wk : Wv;
        int np = w*512 + n;
        Wp[((size_t)(np >> 4)*64 + (k >> 3))*128 + (np & 15)*8 + (k & 7)] = f2bf_bits(src[rem]);
        return;
    }
    __shared__ float T[32][33];
    const int t2 = id - 11264;         // 0..255
    const float* src; u16* dst; int ldsrc, lddst, sr, sc;
    if (t2 < 128) {                    // W1: 512x256, 16x8 tiles
        int tr = t2 >> 3, tc = t2 & 7;
        src = W1; ldsrc = 256; sr = tr*32; sc = tc*32;
        dst = W1T + (size_t)sc*512 + sr; lddst = 512;
    } else {                           // W2: 256x512, 8x16 tiles
        int t = t2 - 128;
        int tr = t >> 4, tc = t & 15;
        src = W2; ldsrc = 512; sr = tr*32; sc = tc*32;
        dst = W2T + (size_t)sc*256 + sr; lddst = 256;
    }
    {
        int r = tt >> 3, c4 = (tt & 7) << 2;
        float4 v = *(const float4*)(src + (size_t)(sr + r)*ldsrc + sc + c4);
        T[r][c4] = v.x; T[r][c4+1] = v.y; T[r][c4+2] = v.z; T[r][c4+3] = v.w;
    }
    __syncthreads();
    {
        int n = tt >> 3, k4 = (tt & 7) << 2;
        u16x4 o = { f2bf_bits(T[k4][n]), f2bf_bits(T[k4+1][n]),
                    f2bf_bits(T[k4+2][n]), f2bf_bits(T[k4+3][n]) };
        *(u16x4*)(dst + (size_t)n*lddst + k4) = o;
    }
}

// ---------------- fused QKV + attention: 1 block = 1 (b,h), 1024 thr / 16 waves ----------------
// r20 + choreography: weight stages issued right after the pass-end barrier so the
// HBM/L2 latency hides under the epilogue VALU (syncthreads' vmcnt drain certifies
// arrival); O-transpose stride 160->144B (odd x 16B) kills the 4-way write conflict.
__global__ __launch_bounds__(1024) void fused_attn_kernel(
    const u16* __restrict__ xp, const u16* __restrict__ Wp,
    const float* __restrict__ bsQ, const float* __restrict__ bsK, const float* __restrict__ bsV,
    u16* __restrict__ O)
{
    extern __shared__ char smem[];
    const int id = blockIdx.x;
    const int xcd = id & 7, slot = id >> 3;
    const int b = xcd*4 + (slot & 3), h = slot >> 2;
    const int tid = threadIdx.x, wave = tid >> 6, lane = tid & 63;
    const int lr = lane & 15, lg = lane >> 4, lr7 = lr & 7;
    char* R0 = smem;                 // 64KB: Wq / Wk staging, then K_lds
    char* R1 = smem + 65536;         // 64KB: q-bounce, then Wv staging, then VT
    const float SCL = 0.18033688011112042f;   // 0.125*log2(e)

    // A fragment base (u16): frag(i, K32-step s) = a0 + i*8192 + s*512
    const u16* a0 = xp + ((size_t)(b*32 + wave*2)*64 + lg)*128 + lr*8;
    // W region bases (u16), each 32768 u16 = 64KB contiguous in packed layout
    const u16* Wqb = Wp + (size_t)h*32768;
    const u16* Wkb = Wp + 262144 + (size_t)h*32768;
    const u16* Wvb = Wp + 524288 + (size_t)h*32768;

    auto stageB = [&](const u16* Wb, char* R) {
        #pragma unroll
        for (int r = 0; r < 4; ++r)
            GLOAD16(Wb + r*8192 + wave*512 + lane*8, R + r*16384 + wave*1024);
    };

    f32x4 acc[2][4];

    // B fragment (bytes in region): j*16384 + s*1024 + lg*256 + lr*16
    auto run_pass = [&](const char* Rb, bool swap) {
        #pragma unroll
        for (int i = 0; i < 2; ++i)
            #pragma unroll
            for (int j = 0; j < 4; ++j) acc[i][j] = f32x4{0.f,0.f,0.f,0.f};
        v8s afA[2], bfA[4], afB[2], bfB[4];
        const char* rb = Rb + lg*256 + lr*16;
        #pragma unroll
        for (int i = 0; i < 2; ++i) afA[i] = *(const v8s*)(a0 + i*8192);
        #pragma unroll
        for (int j = 0; j < 4; ++j) bfA[j] = *(const v8s*)(rb + j*16384);
        #pragma unroll
        for (int tp = 0; tp < 8; ++tp) {
            #pragma unroll
            for (int i = 0; i < 2; ++i) afB[i] = *(const v8s*)(a0 + (2*tp + 1)*512 + i*8192);
            #pragma unroll
            for (int j = 0; j < 4; ++j) bfB[j] = *(const v8s*)(rb + (2*tp + 1)*1024 + j*16384);
            #pragma unroll
            for (int i = 0; i < 2; ++i)
                #pragma unroll
                for (int j = 0; j < 4; ++j)
                    acc[i][j] = swap
                        ? __builtin_amdgcn_mfma_f32_16x16x32_bf16(bfA[j], afA[i], acc[i][j], 0, 0, 0)
                        : __builtin_amdgcn_mfma_f32_16x16x32_bf16(afA[i], bfA[j], acc[i][j], 0, 0, 0);
            if (tp < 7) {
                #pragma unroll
                for (int i = 0; i < 2; ++i) afA[i] = *(const v8s*)(a0 + (2*tp + 2)*512 + i*8192);
                #pragma unroll
                for (int j = 0; j < 4; ++j) bfA[j] = *(const v8s*)(rb + (2*tp + 2)*1024 + j*16384);
            }
            #pragma unroll
            for (int i = 0; i < 2; ++i)
                #pragma unroll
                for (int j = 0; j < 4; ++j)
                    acc[i][j] = swap
                        ? __builtin_amdgcn_mfma_f32_16x16x32_bf16(bfB[j], afB[i], acc[i][j], 0, 0, 0)
                        : __builtin_amdgcn_mfma_f32_16x16x32_bf16(afB[i], bfB[j], acc[i][j], 0, 0, 0);
        }
    };

    // ---- q pass ----
    stageB(Wqb, R0);
    __syncthreads();              // Wq landed
    run_pass(R0, true);
    __syncthreads();              // all waves' Wq reads done
    stageB(Wkb, R0);              // Wk load in flight under q epilogue
    #pragma unroll
    for (int j = 0; j < 4; ++j) {
        float4 b4 = *(const float4*)(bsQ + h*64 + j*16 + lg*4);
        #pragma unroll
        for (int i = 0; i < 2; ++i) {
            int tok = wave*32 + i*16 + lr;
            float v0 = (acc[i][j][0] + b4.x)*SCL, v1 = (acc[i][j][1] + b4.y)*SCL;
            float v2 = (acc[i][j][2] + b4.z)*SCL, v3 = (acc[i][j][3] + b4.w)*SCL;
            int chunk = 2*j + (lg >> 1);
            *(uint2*)(R1 + tok*128 + ((chunk ^ lr7) << 4) + (lg & 1)*8)
                = make_uint2(cvt_pk_bf16(v0, v1), cvt_pk_bf16(v2, v3));
        }
    }
    v8s qa[2][2];
    #pragma unroll
    for (int ti = 0; ti < 2; ++ti) {
        const char* qr = R1 + (wave*32 + ti*16 + lr)*128;
        qa[ti][0] = *(const v8s*)(qr + ((lg ^ lr7) << 4));
        qa[ti][1] = *(const v8s*)(qr + (((4 | lg) ^ lr7) << 4));
    }
    __syncthreads();              // Wk landed (vmcnt drain) + all qa reads done

    // ---- k pass ----
    run_pass(R0, true);
    __syncthreads();              // all Wk reads done; R1 (q-bounce) dead
    stageB(Wvb, R1);              // Wv load in flight under K epilogue
    #pragma unroll
    for (int j = 0; j < 4; ++j) {
        float4 b4 = *(const float4*)(bsK + h*64 + j*16 + lg*4);
        #pragma unroll
        for (int i = 0; i < 2; ++i) {
            int tok = wave*32 + i*16 + lr;
            float v0 = acc[i][j][0] + b4.x, v1 = acc[i][j][1] + b4.y;
            float v2 = acc[i][j][2] + b4.z, v3 = acc[i][j][3] + b4.w;
            int chunk = 2*j + (lg >> 1);
            *(uint2*)(R0 + tok*128 + ((chunk ^ lr7) << 4) + (lg & 1)*8)
                = make_uint2(cvt_pk_bf16(v0, v1), cvt_pk_bf16(v2, v3));
        }
    }
    __syncthreads();              // Wv landed + K visible

    // ---- v pass ----
    run_pass(R1, false);
    __syncthreads();              // all Wv reads done before VT overwrites R1
    #pragma unroll
    for (int j = 0; j < 4; ++j) {
        #pragma unroll
        for (int i = 0; i < 2; ++i) {
            int d = j*16 + lr;
            float bv = bsV[h*64 + d];
            int chunk = wave*4 + 2*i + (lg >> 1);
            *(uint2*)(R1 + d*1024 + ((chunk ^ lr7) << 4) + (lg & 1)*8)
                = make_uint2(cvt_pk_bf16(acc[i][j][0] + bv, acc[i][j][1] + bv),
                             cvt_pk_bf16(acc[i][j][2] + bv, acc[i][j][3] + bv));
        }
    }
    __syncthreads();              // VT ready

    // ---- attention core: each wave handles 32 queries ----
    const int q0 = wave*32;
    f32x4 o[2][4] = {};
    float ssum[2] = {0.f, 0.f};

    #pragma unroll 1
    for (int c = 0; c < 16; ++c) {
        const char* kr0 = R0 + ((2*c  )*16 + lr)*128;
        const char* kr1 = R0 + ((2*c+1)*16 + lr)*128;
        v8s kA0 = *(const v8s*)(kr0 + ((lg ^ lr7) << 4));
        v8s kA1 = *(const v8s*)(kr0 + (((4|lg) ^ lr7) << 4));
        v8s kB0 = *(const v8s*)(kr1 + ((lg ^ lr7) << 4));
        v8s kB1 = *(const v8s*)(kr1 + (((4|lg) ^ lr7) << 4));
        v8s vf[4];
        #pragma unroll
        for (int dt = 0; dt < 4; ++dt) {
            const char* vr = R1 + (dt*16 + lr)*1024;
            int c0 = c*4 + (lg >> 1), rem = (lg & 1)*8;
            uint2 lo = *(const uint2*)(vr + (((c0    ) ^ lr7) << 4) + rem);
            uint2 hi = *(const uint2*)(vr + (((c0 + 2) ^ lr7) << 4) + rem);
            uint4 u = make_uint4(lo.x, lo.y, hi.x, hi.y);
            vf[dt] = *(v8s*)&u;
        }
        #pragma unroll
        for (int ti = 0; ti < 2; ++ti) {
            __builtin_amdgcn_s_setprio(1);
            f32x4 s0 = {0.f,0.f,0.f,0.f}, s1 = {0.f,0.f,0.f,0.f};
            s0 = __builtin_amdgcn_mfma_f32_16x16x32_bf16(kA0, qa[ti][0], s0, 0, 0, 0);
            s0 = __builtin_amdgcn_mfma_f32_16x16x32_bf16(kA1, qa[ti][1], s0, 0, 0, 0);
            s1 = __builtin_amdgcn_mfma_f32_16x16x32_bf16(kB0, qa[ti][0], s1, 0, 0, 0);
            s1 = __builtin_amdgcn_mfma_f32_16x16x32_bf16(kB1, qa[ti][1], s1, 0, 0, 0);
            __builtin_amdgcn_s_setprio(0);
            float p0 = exp2f(s0[0]), p1 = exp2f(s0[1]), p2 = exp2f(s0[2]), p3 = exp2f(s0[3]);
            float r0 = exp2f(s1[0]), r1 = exp2f(s1[1]), r2 = exp2f(s1[2]), r3 = exp2f(s1[3]);
            ssum[ti] += ((p0 + p1) + (p2 + p3)) + ((r0 + r1) + (r2 + r3));
            unsigned a0w = cvt_pk_bf16(p0, p1), a1w = cvt_pk_bf16(p2, p3);
            unsigned b0w = cvt_pk_bf16(r0, r1), b1w = cvt_pk_bf16(r2, r3);
            uint4 pu = make_uint4(a0w, a1w, b0w, b1w);
            v8s pb = *(v8s*)&pu;
            __builtin_amdgcn_s_setprio(1);
            #pragma unroll
            for (int dt = 0; dt < 4; ++dt)
                o[ti][dt] = __builtin_amdgcn_mfma_f32_16x16x32_bf16(vf[dt], pb, o[ti][dt], 0, 0, 0);
            __builtin_amdgcn_s_setprio(0);
        }
    }

    __syncthreads();   // K/VT dead; LDS reused for O transpose

    float rinv[2];
    #pragma unroll
    for (int ti = 0; ti < 2; ++ti) {
        float v = ssum[ti];
        v += __shfl_xor(v, 16);
        v += __shfl_xor(v, 32);
        rinv[ti] = 1.f / v;
    }

    char* ow = (char*)smem + wave*4608;      // 32 rows x 144B per wave (72KB total)
    #pragma unroll
    for (int ti = 0; ti < 2; ++ti) {
        #pragma unroll
        for (int dt = 0; dt < 4; ++dt) {
            unsigned d0 = cvt_pk_bf16(o[ti][dt][0]*rinv[ti], o[ti][dt][1]*rinv[ti]);
            unsigned d1 = cvt_pk_bf16(o[ti][dt][2]*rinv[ti], o[ti][dt][3]*rinv[ti]);
            *(uint2*)(ow + (ti*16 + lr)*144 + dt*32 + lg*8) = make_uint2(d0, d1);
        }
    }
    __asm__ volatile("s_waitcnt lgkmcnt(0)" ::: "memory");
    #pragma unroll
    for (int it = 0; it < 4; ++it) {
        int rr2 = it*8 + (lane >> 3);
        uint4 v = *(const uint4*)(ow + rr2*144 + (lane & 7)*16);
        *(uint4*)(O + (size_t)(b*NE + q0 + rr2)*DMODEL + h*EMB + (lane & 7)*8) = v;
    }
}

// ---------------- grand fused LN1 + FF1 + relu + FF2 + residual + LN2 (r16, unchanged) ----------------
__global__ __launch_bounds__(512) void ffln_kernel(
    const u16* __restrict__ At, const u16* __restrict__ xb,
    const float* __restrict__ g1, const float* __restrict__ be1,
    const u16* __restrict__ W1T, const float* __restrict__ b1,
    const u16* __restrict__ W2T, const float* __restrict__ b2,
    const float* __restrict__ g2, const float* __restrict__ be2,
    float* __restrict__ out)
{
    extern __shared__ char smem[];
    char* H    = smem;
    char* F1   = smem + 65536;
    char* BSTa = smem + 98304;
    float* Ps = (float*)(smem + 131072);
    float* Pq = Ps + 128;

    const int tid = threadIdx.x, wave = tid >> 6, lane = tid & 63;
    const int lr = lane & 15, lg = lane >> 4, lr7 = lr & 7;
    const int r0 = blockIdx.x * 64;

    #pragma unroll
    for (int it = 0; it < 8; ++it) {
        int r = wave*8 + it;
        uint4 av = *(const uint4*)(At + (size_t)(r0 + r)*512 + lane*8);
        uint4 xv = *(const uint4*)(xb + (size_t)(r0 + r)*512 + lane*8);
        float v0 = bflo(av.x) + bflo(xv.x), v1 = bfhi(av.x) + bfhi(xv.x);
        float v2 = bflo(av.y) + bflo(xv.y), v3 = bfhi(av.y) + bfhi(xv.y);
        float v4 = bflo(av.z) + bflo(xv.z), v5 = bfhi(av.z) + bfhi(xv.z);
        float v6 = bflo(av.w) + bflo(xv.w), v7 = bfhi(av.w) + bfhi(xv.w);
        float s = ((v0+v1)+(v2+v3)) + ((v4+v5)+(v6+v7));
        float q = ((v0*v0+v1*v1)+(v2*v2+v3*v3)) + ((v4*v4+v5*v5)+(v6*v6+v7*v7));
        #pragma unroll
        for (int d = 1; d < 64; d <<= 1) { s += __shfl_xor(s, d); q += __shfl_xor(q, d); }
        float mu = s * (1.f/512.f);
        float rs = rsqrtf(q * (1.f/512.f) - mu*mu + 1e-5f);
        float4 gA = *(const float4*)(g1 + lane*8), gB = *(const float4*)(g1 + lane*8 + 4);
        float4 eA = *(const float4*)(be1 + lane*8), eB = *(const float4*)(be1 + lane*8 + 4);
        float h0 = (v0-mu)*rs*gA.x + eA.x, h1 = (v1-mu)*rs*gA.y + eA.y;
        float h2 = (v2-mu)*rs*gA.z + eA.z, h3 = (v3-mu)*rs*gA.w + eA.w;
        float h4 = (v4-mu)*rs*gB.x + eB.x, h5 = (v5-mu)*rs*gB.y + eB.y;
        float h6 = (v6-mu)*rs*gB.z + eB.z, h7 = (v7-mu)*rs*gB.w + eB.w;
        uint4 hw = make_uint4(cvt_pk_bf16(h0,h1), cvt_pk_bf16(h2,h3),
                              cvt_pk_bf16(h4,h5), cvt_pk_bf16(h6,h7));
        *(uint4*)(H + r*1024 + ((lane ^ (r & 7)) << 4)) = hw;
    }
    __syncthreads();

    const int wr = (wave & 3)*16, wcB = (wave >> 2)*128;

    auto stageW1 = [&](char* buf, int s8) {
        int k0 = s8*64;
        #pragma unroll
        for (int i = 0; i < 4; ++i) {
            int slot = i*512 + tid;
            int row = slot >> 3, ch = slot & 7;
            GLOAD16(W1T + (size_t)row*512 + k0 + ((ch ^ (row & 7)) << 3),
                    buf + i*8192 + wave*1024);
        }
    };
    stageW1(BSTa, 0);
    f32x4 acc1[8] = {};
    #pragma unroll
    for (int s8 = 0; s8 < 8; ++s8) {
        char* cur = (s8 & 1) ? F1 : BSTa;
        asm volatile("s_waitcnt vmcnt(0)" ::: "memory");
        __builtin_amdgcn_s_barrier();
        if (s8 + 1 < 8) stageW1((s8 & 1) ? BSTa : F1, s8 + 1);
        #pragma unroll
        for (int kk = 0; kk < 2; ++kk) {
            v8s af = *(const v8s*)(H + (wr + lr)*1024 + (((s8*8 + kk*4 + lg) ^ lr7) << 4));
            v8s bf[8];
            #pragma unroll
            for (int j = 0; j < 8; ++j)
                bf[j] = *(const v8s*)(cur + (wcB + j*16 + lr)*128 + ((((kk<<2)|lg) ^ lr7) << 4));
            #pragma unroll
            for (int j = 0; j < 8; ++j)
                acc1[j] = __builtin_amdgcn_mfma_f32_16x16x32_bf16(bf[j], af, acc1[j], 0, 0, 0);
        }
    }
    __syncthreads();

    {
        int row = wr + lr;
        #pragma unroll
        for (int j = 0; j < 8; ++j) {
            int col0 = wcB + j*16 + lg*4;
            float4 b4 = *(const float4*)(b1 + col0);
            float v0 = fmaxf(acc1[j][0] + b4.x, 0.f), v1 = fmaxf(acc1[j][1] + b4.y, 0.f);
            float v2 = fmaxf(acc1[j][2] + b4.z, 0.f), v3 = fmaxf(acc1[j][3] + b4.w, 0.f);
            *(uint2*)(F1 + row*512 + (((col0 >> 3) ^ (row & 7)) << 4) + (col0 & 7)*2)
                = make_uint2(cvt_pk_bf16(v0, v1), cvt_pk_bf16(v2, v3));
        }
    }

    const int row = wr + lr;
    uint2 hres[2][8];
    #pragma unroll
    for (int nh = 0; nh < 2; ++nh)
        #pragma unroll
        for (int j = 0; j < 8; ++j) {
            int col0 = nh*256 + wcB + j*16 + lg*4;
            hres[nh][j] = *(const uint2*)(H + row*1024 +
                            ((((col0 & 511) >> 3) ^ (row & 7)) << 4) + (col0 & 7)*2);
        }
    __syncthreads();

    auto stageW2 = [&](char* buf, int g) {
        int nh = g >> 2, k0 = (g & 3)*64;
        #pragma unroll
        for (int i = 0; i < 4; ++i) {
            int slot = i*512 + tid;
            int rw = slot >> 3, ch = slot & 7;
            GLOAD16(W2T + (size_t)(nh*256 + rw)*256 + k0 + ((ch ^ (rw & 7)) << 3),
                    buf + i*8192 + wave*1024);
        }
    };
    stageW2(H, 0);
    f32x4 acc2[2][8] = {};
    #pragma unroll
    for (int g = 0; g < 8; ++g) {
        char* cur = (g & 1) ? (H + 32768) : H;
        asm volatile("s_waitcnt vmcnt(0)" ::: "memory");
        __builtin_amdgcn_s_barrier();
        if (g + 1 < 8) stageW2((g & 1) ? H : (H + 32768), g + 1);
        const int nh = g >> 2, s4 = g & 3;
        #pragma unroll
        for (int kk = 0; kk < 2; ++kk) {
            v8s af = *(const v8s*)(F1 + (wr + lr)*512 + (((s4*8 + kk*4 + lg) ^ lr7) << 4));
            v8s bf[8];
            #pragma unroll
            for (int j = 0; j < 8; ++j)
                bf[j] = *(const v8s*)(cur + (wcB + j*16 + lr)*128 + ((((kk<<2)|lg) ^ lr7) << 4));
            #pragma unroll
            for (int j = 0; j < 8; ++j)
                acc2[nh][j] = __builtin_amdgcn_mfma_f32_16x16x32_bf16(bf[j], af, acc2[nh][j], 0, 0, 0);
        }
    }

    float s = 0.f, q = 0.f;
    #pragma unroll
    for (int nh = 0; nh < 2; ++nh) {
        #pragma unroll
        for (int j = 0; j < 8; ++j) {
            int col0 = nh*256 + wcB + j*16 + lg*4;
            float4 b4 = *(const float4*)(b2 + col0);
            uint2 hh = hres[nh][j];
            f32x4 a = acc2[nh][j];
            a[0] += b4.x + bflo(hh.x); a[1] += b4.y + bfhi(hh.x);
            a[2] += b4.z + bflo(hh.y); a[3] += b4.w + bfhi(hh.y);
            acc2[nh][j] = a;
            s += (a[0]+a[1]) + (a[2]+a[3]);
            q += (a[0]*a[0]+a[1]*a[1]) + (a[2]*a[2]+a[3]*a[3]);
        }
    }
    s += __shfl_xor(s, 16); s += __shfl_xor(s, 32);
    q += __shfl_xor(q, 16); q += __shfl_xor(q, 32);
    __syncthreads();
    if (lg == 0) { Ps[row*2 + (wave >> 2)] = s; Pq[row*2 + (wave >> 2)] = q; }
    __syncthreads();
    float st = Ps[row*2] + Ps[row*2 + 1];
    float qt = Pq[row*2] + Pq[row*2 + 1];
    float mu = st * (1.f/512.f);
    float rs = rsqrtf(qt * (1.f/512.f) - mu*mu + 1e-5f);

    #pragma unroll
    for (int nh = 0; nh < 2; ++nh) {
        #pragma unroll
        for (int j = 0; j < 8; ++j) {
            int col0 = nh*256 + wcB + j*16 + lg*4;
            float4 gg = *(const float4*)(g2 + col0);
            float4 ee = *(const float4*)(be2 + col0);
            f32x4 a = acc2[nh][j];
            float4 o;
            o.x = (a[0]-mu)*rs*gg.x + ee.x;
            o.y = (a[1]-mu)*rs*gg.y + ee.y;
            o.z = (a[2]-mu)*rs*gg.z + ee.z;
            o.w = (a[3]-mu)*rs*gg.w + ee.w;
            *(float4*)(out + (size_t)(r0 + row)*512 + col0) = o;
        }
    }
}

// ---------------- launcher ----------------

extern "C" void kernel_launch(void* const* d_in, const int* in_sizes, int n_in,
                              void* d_out, int out_size, void* d_ws, size_t ws_size,
                              hipStream_t stream)
{
    const float* x   = (const float*)d_in[0];
    const float* Wq  = (const float*)d_in[1];
    const float* bq  = (const float*)d_in[2];
    const float* Wk  = (const float*)d_in[3];
    const float* bk  = (const float*)d_in[4];
    const float* Wv  = (const float*)d_in[5];
    const float* bv  = (const float*)d_in[6];
    const float* W1  = (const float*)d_in[7];
    const float* bf1 = (const float*)d_in[8];
    const float* W2  = (const float*)d_in[9];
    const float* bf2 = (const float*)d_in[10];
    const float* g1  = (const float*)d_in[11];
    const float* be1 = (const float*)d_in[12];
    const float* g2  = (const float*)d_in[13];
    const float* be2 = (const float*)d_in[14];

    char* ws = (char*)d_ws;
    const size_t MB = 1ull << 20;
    const size_t KB = 1024;
    u16* xb    = (u16*)(ws + 0);          // x bf16 linear — live through ffln
    u16* xp    = (u16*)(ws + 16*MB);      // x packed fragments
    u16* attnb = (u16*)(ws + 32*MB);      // attention output
    u16* Wp    = (u16*)(ws + 48*MB);                 // Wqkv packed [96][64][16][8]
    u16* W1T   = (u16*)(ws + 48*MB + 1536*KB);       // [256][512]
    u16* W2T   = (u16*)(ws + 48*MB + 1792*KB);       // [512][256]
    (void)ws_size; (void)in_sizes; (void)n_in; (void)out_size;

    cvt_all_kernel<<<11520, 256, 0, stream>>>(x, xb, xp, Wq, Wk, Wv, W1, W2, Wp, W1T, W2T);

    fused_attn_kernel<<<256, 1024, 131072, stream>>>(xp, Wp, bq, bk, bv, attnb);

    ffln_kernel<<<256, 512, 132096, stream>>>(attnb, xb, g1, be1, W1T, bf1, W2T, bf2,
                                              g2, be2, (float*)d_out);
}